// Round 1
// baseline (356.098 us; speedup 1.0000x reference)
//
#include <hip/hip_runtime.h>
#include <cstdint>
#include <cstddef>

#define BB   32768
#define DD   8
#define LLV  16
#define TBL  524288
#define CCH  2
#define HID  512

// primes mod 2^32
__device__ __constant__ uint32_t PR[8] = {
    2654436881u, 1620619981u, 1500450271u, 3267000013u,
    1459886047u, 4093082899u,  986956175u, 3628273133u
};

// ---------------- encoding: one thread per (b, l) ----------------
__global__ __launch_bounds__(256) void k_encode(
    const float* __restrict__ x, const float* __restrict__ T,
    const float* __restrict__ Karr, float* __restrict__ h0)
{
    int t = blockIdx.x * 256 + threadIdx.x;    // t = b*16 + l
    int b = t >> 4;
    int l = t & 15;

    const float4 x0 = *(const float4*)(x + (size_t)b * DD);
    const float4 x1 = *(const float4*)(x + (size_t)b * DD + 4);
    float xs[8] = {x0.x, x0.y, x0.z, x0.w, x1.x, x1.y, x1.z, x1.w};

    float Kl = Karr[l];

    float fr[8];
    int   base[8];
    float cs = 0.f;
#pragma unroll
    for (int i = 0; i < 8; i++) {
        cs += xs[i];                 // sequential fp32 cumsum (matches np)
        float p = cs * Kl;
        fr[i]   = p - truncf(p);     // trunc-fractional (sign of p)
        base[i] = (int)floorf(p);    // floor for lattice base
    }

    // sort fr ascending into c[8] (19-comparator network)
    float c[8];
#pragma unroll
    for (int i = 0; i < 8; i++) c[i] = fr[i];
#define CE(a_, b_) { float lo_ = fminf(c[a_], c[b_]); float hi_ = fmaxf(c[a_], c[b_]); c[a_] = lo_; c[b_] = hi_; }
    CE(0,1) CE(2,3) CE(4,5) CE(6,7)
    CE(0,2) CE(1,3) CE(4,6) CE(5,7)
    CE(1,2) CE(5,6) CE(0,4) CE(3,7)
    CE(1,5) CE(2,6)
    CE(1,4) CE(3,6)
    CE(2,4) CE(3,5)
    CE(3,4)
#undef CE

    float f0 = 0.f, f1 = 0.f;
    float prevc = 0.f;
#pragma unroll
    for (int j = 0; j < 9; j++) {
        float cj = (j < 8) ? c[j] : 1.0f;
        uint32_t h = 0;
        int prev = 0;
#pragma unroll
        for (int i = 0; i < 8; i++) {
            int ai = base[i] + (fr[i] >= cj ? 1 : 0);
            h ^= (uint32_t)(ai - prev) * PR[i];   // int32 wraparound == uint32 mult
            prev = ai;
        }
        uint32_t idx = h & (TBL - 1);             // python mod of 2^19 == low 19 bits
        const float2 tv = *(const float2*)(T + (((size_t)l * TBL + idx) << 1));
        float w = cj - prevc;                     // barycentric weight
        prevc = cj;
        f0 = fmaf(tv.x, w, f0);
        f1 = fmaf(tv.y, w, f1);
    }
    f0 /= Kl;
    f1 /= Kl;

    float* row = h0 + (size_t)b * 40;
    *(float2*)(row + 8 + l * 2) = make_float2(f0, f1);
    if (l == 0) {
        *(float4*)(row)     = x0;
        *(float4*)(row + 4) = x1;
    }
}

// ---------------- gemm1: h1 = relu(h0 @ W1^T + b1), weights-stationary ----------------
#define MB1 128
__global__ __launch_bounds__(256) void k_gemm1(
    const float* __restrict__ h0, const float* __restrict__ w1,
    const float* __restrict__ b1, float* __restrict__ h1)
{
    __shared__ float sh[MB1 * 40];
    int o  = blockIdx.x * 256 + threadIdx.x;   // output index 0..511
    int b0 = blockIdx.y * MB1;

    float wr[40];
#pragma unroll
    for (int k = 0; k < 40; k += 4) {
        float4 v = *(const float4*)(w1 + (size_t)o * 40 + k);
        wr[k+0] = v.x; wr[k+1] = v.y; wr[k+2] = v.z; wr[k+3] = v.w;
    }
    float bias = b1[o];

    for (int i = threadIdx.x; i < MB1 * 40 / 4; i += 256) {
        *(float4*)&sh[i * 4] = *(const float4*)(h0 + (size_t)b0 * 40 + i * 4);
    }
    __syncthreads();

    for (int s = 0; s < MB1; s++) {
        float acc = bias;
#pragma unroll
        for (int k4 = 0; k4 < 10; k4++) {
            float4 hv = *(float4*)&sh[s * 40 + k4 * 4];
            acc = fmaf(wr[k4*4+0], hv.x, acc);
            acc = fmaf(wr[k4*4+1], hv.y, acc);
            acc = fmaf(wr[k4*4+2], hv.z, acc);
            acc = fmaf(wr[k4*4+3], hv.w, acc);
        }
        h1[(size_t)(b0 + s) * HID + o] = fmaxf(acc, 0.f);
    }
}

// ---------------- gemm2: h2 = relu(h1 @ W2^T + b2), 64x64 tile fp32 ----------------
__global__ __launch_bounds__(256) void k_gemm2(
    const float* __restrict__ h1, const float* __restrict__ w2,
    const float* __restrict__ b2, float* __restrict__ h2)
{
    __shared__ float As[32 * 68];   // [k][b], padded stride 68
    __shared__ float Bs[32 * 68];   // [k][o]
    int tx = threadIdx.x & 15;      // b-sub
    int ty = threadIdx.x >> 4;      // o-sub
    int b0 = blockIdx.x * 64;
    int o0 = blockIdx.y * 64;

    float acc[4][4] = {};

    for (int k0 = 0; k0 < HID; k0 += 32) {
#pragma unroll
        for (int rep = 0; rep < 2; rep++) {
            int id = threadIdx.x + rep * 256;
            int r  = id >> 3;
            int c4 = (id & 7) * 4;
            float4 va = *(const float4*)(h1 + (size_t)(b0 + r) * HID + k0 + c4);
            As[(c4+0)*68 + r] = va.x; As[(c4+1)*68 + r] = va.y;
            As[(c4+2)*68 + r] = va.z; As[(c4+3)*68 + r] = va.w;
            float4 vb = *(const float4*)(w2 + (size_t)(o0 + r) * HID + k0 + c4);
            Bs[(c4+0)*68 + r] = vb.x; Bs[(c4+1)*68 + r] = vb.y;
            Bs[(c4+2)*68 + r] = vb.z; Bs[(c4+3)*68 + r] = vb.w;
        }
        __syncthreads();
#pragma unroll
        for (int k = 0; k < 32; k++) {
            float4 a  = *(float4*)&As[k * 68 + tx * 4];
            float4 bv = *(float4*)&Bs[k * 68 + ty * 4];
            acc[0][0] = fmaf(a.x, bv.x, acc[0][0]);
            acc[0][1] = fmaf(a.x, bv.y, acc[0][1]);
            acc[0][2] = fmaf(a.x, bv.z, acc[0][2]);
            acc[0][3] = fmaf(a.x, bv.w, acc[0][3]);
            acc[1][0] = fmaf(a.y, bv.x, acc[1][0]);
            acc[1][1] = fmaf(a.y, bv.y, acc[1][1]);
            acc[1][2] = fmaf(a.y, bv.z, acc[1][2]);
            acc[1][3] = fmaf(a.y, bv.w, acc[1][3]);
            acc[2][0] = fmaf(a.z, bv.x, acc[2][0]);
            acc[2][1] = fmaf(a.z, bv.y, acc[2][1]);
            acc[2][2] = fmaf(a.z, bv.z, acc[2][2]);
            acc[2][3] = fmaf(a.z, bv.w, acc[2][3]);
            acc[3][0] = fmaf(a.w, bv.x, acc[3][0]);
            acc[3][1] = fmaf(a.w, bv.y, acc[3][1]);
            acc[3][2] = fmaf(a.w, bv.z, acc[3][2]);
            acc[3][3] = fmaf(a.w, bv.w, acc[3][3]);
        }
        __syncthreads();
    }

    float bo[4];
#pragma unroll
    for (int j = 0; j < 4; j++) bo[j] = b2[o0 + ty * 4 + j];
#pragma unroll
    for (int i = 0; i < 4; i++) {
        int b = b0 + tx * 4 + i;
        float4 ov;
        ov.x = fmaxf(acc[i][0] + bo[0], 0.f);
        ov.y = fmaxf(acc[i][1] + bo[1], 0.f);
        ov.z = fmaxf(acc[i][2] + bo[2], 0.f);
        ov.w = fmaxf(acc[i][3] + bo[3], 0.f);
        *(float4*)(h2 + (size_t)b * HID + o0 + ty * 4) = ov;
    }
}

// ---------------- heads: action/value from h2, one wave per sample ----------------
__global__ __launch_bounds__(256) void k_heads(
    const float* __restrict__ h2, const float* __restrict__ aw,
    const float* __restrict__ ab, const float* __restrict__ vw,
    const float* __restrict__ vb, float* __restrict__ out)
{
    int wave = threadIdx.x >> 6;
    int lane = threadIdx.x & 63;
    int s = blockIdx.x * 4 + wave;

    const float* hr = h2 + (size_t)s * HID + lane * 8;
    float4 ha = *(const float4*)hr;
    float4 hb = *(const float4*)(hr + 4);
    float hv[8] = {ha.x, ha.y, ha.z, ha.w, hb.x, hb.y, hb.z, hb.w};

    float part[5];
#pragma unroll
    for (int m = 0; m < 5; m++) {
        const float* wrow = ((m < 4) ? (aw + (size_t)m * HID) : vw) + lane * 8;
        float4 wa = *(const float4*)wrow;
        float4 wb = *(const float4*)(wrow + 4);
        float p = hv[0] * wa.x;
        p = fmaf(hv[1], wa.y, p);
        p = fmaf(hv[2], wa.z, p);
        p = fmaf(hv[3], wa.w, p);
        p = fmaf(hv[4], wb.x, p);
        p = fmaf(hv[5], wb.y, p);
        p = fmaf(hv[6], wb.z, p);
        p = fmaf(hv[7], wb.w, p);
        part[m] = p;
    }
#pragma unroll
    for (int m = 0; m < 5; m++) {
        float v = part[m];
#pragma unroll
        for (int off = 32; off > 0; off >>= 1) v += __shfl_xor(v, off);
        if (lane == 0) {
            if (m < 4) out[(size_t)s * 4 + m] = v + ab[m];
            else       out[(size_t)BB * 4 + s] = v + vb[0];
        }
    }
}

extern "C" void kernel_launch(void* const* d_in, const int* in_sizes, int n_in,
                              void* d_out, int out_size, void* d_ws, size_t ws_size,
                              hipStream_t stream)
{
    const float* x    = (const float*)d_in[0];
    const float* T    = (const float*)d_in[1];
    const float* K    = (const float*)d_in[2];
    const float* l1w  = (const float*)d_in[3];
    const float* l1b  = (const float*)d_in[4];
    const float* l2w  = (const float*)d_in[5];
    const float* l2b  = (const float*)d_in[6];
    const float* actw = (const float*)d_in[7];
    const float* actb = (const float*)d_in[8];
    const float* valw = (const float*)d_in[9];
    const float* valb = (const float*)d_in[10];
    float* out = (float*)d_out;

    char* ws = (char*)d_ws;
    float* h0 = (float*)ws;                                        // B*40 fp32
    float* h1 = (float*)(ws + (size_t)BB * 40 * 4);                // B*512 fp32
    float* h2 = (float*)(ws + (size_t)BB * 40 * 4 + (size_t)BB * HID * 4);

    k_encode<<<BB * LLV / 256, 256, 0, stream>>>(x, T, K, h0);
    k_gemm1<<<dim3(2, BB / MB1), 256, 0, stream>>>(h0, l1w, l1b, h1);
    k_gemm2<<<dim3(BB / 64, HID / 64), 256, 0, stream>>>(h1, l2w, l2b, h2);
    k_heads<<<BB / 4, 256, 0, stream>>>(h2, actw, actb, valw, valb, out);
}

// Round 2
// 175.847 us; speedup vs baseline: 2.0250x; 2.0250x over previous
//
#include <hip/hip_runtime.h>
#include <cstdint>
#include <cstddef>

#define BB   32768
#define DD   8
#define LLV  16
#define TBL  524288
#define HID  512

typedef __attribute__((ext_vector_type(8))) short short8;
typedef __attribute__((ext_vector_type(8))) unsigned short u16x8;
typedef __attribute__((ext_vector_type(4))) float f32x4;

// primes mod 2^32
__device__ __constant__ uint32_t PR[8] = {
    2654436881u, 1620619981u, 1500450271u, 3267000013u,
    1459886047u, 4093082899u,  986956175u, 3628273133u
};

__device__ __forceinline__ unsigned short f2bf(float f) {
    uint32_t u = __float_as_uint(f);
    uint32_t r = (u + 0x7fffu + ((u >> 16) & 1u)) >> 16;   // RNE
    return (unsigned short)r;
}
__device__ __forceinline__ float bf2f(unsigned short u) {
    return __uint_as_float(((uint32_t)u) << 16);
}

__device__ __forceinline__ void gload_lds16(const void* gsrc, void* ldst) {
    __builtin_amdgcn_global_load_lds(
        (const __attribute__((address_space(1))) unsigned int*)gsrc,
        (__attribute__((address_space(3))) unsigned int*)ldst,
        16, 0, 0);
}

// ---------------- encoding: one thread per (b, l) ----------------
__global__ __launch_bounds__(256) void k_encode(
    const float* __restrict__ x, const float* __restrict__ T,
    const float* __restrict__ Karr, float* __restrict__ h0)
{
    int t = blockIdx.x * 256 + threadIdx.x;    // t = b*16 + l
    int b = t >> 4;
    int l = t & 15;

    const float4 x0 = *(const float4*)(x + (size_t)b * DD);
    const float4 x1 = *(const float4*)(x + (size_t)b * DD + 4);
    float xs[8] = {x0.x, x0.y, x0.z, x0.w, x1.x, x1.y, x1.z, x1.w};

    float Kl = Karr[l];

    float fr[8];
    int   base[8];
    float cs = 0.f;
#pragma unroll
    for (int i = 0; i < 8; i++) {
        cs += xs[i];                 // sequential fp32 cumsum (matches np)
        float p = cs * Kl;
        fr[i]   = p - truncf(p);     // trunc-fractional
        base[i] = (int)floorf(p);    // floor for lattice base
    }

    float c[8];
#pragma unroll
    for (int i = 0; i < 8; i++) c[i] = fr[i];
#define CE(a_, b_) { float lo_ = fminf(c[a_], c[b_]); float hi_ = fmaxf(c[a_], c[b_]); c[a_] = lo_; c[b_] = hi_; }
    CE(0,1) CE(2,3) CE(4,5) CE(6,7)
    CE(0,2) CE(1,3) CE(4,6) CE(5,7)
    CE(1,2) CE(5,6) CE(0,4) CE(3,7)
    CE(1,5) CE(2,6)
    CE(1,4) CE(3,6)
    CE(2,4) CE(3,5)
    CE(3,4)
#undef CE

    float f0 = 0.f, f1 = 0.f;
    float prevc = 0.f;
#pragma unroll
    for (int j = 0; j < 9; j++) {
        float cj = (j < 8) ? c[j] : 1.0f;
        uint32_t h = 0;
        int prev = 0;
#pragma unroll
        for (int i = 0; i < 8; i++) {
            int ai = base[i] + (fr[i] >= cj ? 1 : 0);
            h ^= (uint32_t)(ai - prev) * PR[i];
            prev = ai;
        }
        uint32_t idx = h & (TBL - 1);
        const float2 tv = *(const float2*)(T + (((size_t)l * TBL + idx) << 1));
        float w = cj - prevc;
        prevc = cj;
        f0 = fmaf(tv.x, w, f0);
        f1 = fmaf(tv.y, w, f1);
    }
    f0 /= Kl;
    f1 /= Kl;

    float* row = h0 + (size_t)b * 40;
    *(float2*)(row + 8 + l * 2) = make_float2(f0, f1);
    if (l == 0) {
        *(float4*)(row)     = x0;
        *(float4*)(row + 4) = x1;
    }
}

// ---------------- gemm1: h1 = relu(h0 @ W1^T + b1) -> bf16 ----------------
#define MB1 128
__global__ __launch_bounds__(256) void k_gemm1(
    const float* __restrict__ h0, const float* __restrict__ w1,
    const float* __restrict__ b1, unsigned short* __restrict__ h1)
{
    __shared__ float sh[MB1 * 40];
    int o  = blockIdx.x * 256 + threadIdx.x;   // output index 0..511
    int b0 = blockIdx.y * MB1;

    float wr[40];
#pragma unroll
    for (int k = 0; k < 40; k += 4) {
        float4 v = *(const float4*)(w1 + (size_t)o * 40 + k);
        wr[k+0] = v.x; wr[k+1] = v.y; wr[k+2] = v.z; wr[k+3] = v.w;
    }
    float bias = b1[o];

    for (int i = threadIdx.x; i < MB1 * 40 / 4; i += 256) {
        *(float4*)&sh[i * 4] = *(const float4*)(h0 + (size_t)b0 * 40 + i * 4);
    }
    __syncthreads();

    for (int s = 0; s < MB1; s++) {
        float acc = bias;
#pragma unroll
        for (int k4 = 0; k4 < 10; k4++) {
            float4 hv = *(float4*)&sh[s * 40 + k4 * 4];
            acc = fmaf(wr[k4*4+0], hv.x, acc);
            acc = fmaf(wr[k4*4+1], hv.y, acc);
            acc = fmaf(wr[k4*4+2], hv.z, acc);
            acc = fmaf(wr[k4*4+3], hv.w, acc);
        }
        h1[(size_t)(b0 + s) * HID + o] = f2bf(fmaxf(acc, 0.f));
    }
}

// ---------------- w2 fp32 -> bf16 ----------------
__global__ __launch_bounds__(256) void k_cvt(
    const float* __restrict__ w, unsigned short* __restrict__ o)
{
    int i = blockIdx.x * 256 + threadIdx.x;     // each converts 4
    float4 v = *(const float4*)(w + (size_t)i * 4);
    ushort4 r;
    r.x = f2bf(v.x); r.y = f2bf(v.y); r.z = f2bf(v.z); r.w = f2bf(v.w);
    *(ushort4*)(o + (size_t)i * 4) = r;
}

// ---------------- gemm2: bf16 MFMA 128x128 tile, XOR-swizzled LDS ----------------
#define BM 128
#define BN 128
#define BKE 64

__global__ __launch_bounds__(256) void k_gemm2m(
    const unsigned short* __restrict__ h1, const unsigned short* __restrict__ w2,
    const float* __restrict__ b2, unsigned short* __restrict__ h2)
{
    __shared__ unsigned short As[BM * BKE];   // physical (swizzled) layout
    __shared__ unsigned short Bs[BN * BKE];

    const int tid  = threadIdx.x;
    const int wid  = tid >> 6;
    const int lane = tid & 63;
    const int wm = wid >> 1, wn = wid & 1;
    const int lr = lane & 15;
    const int kg = lane >> 4;

    const int b0 = blockIdx.x * BM;
    const int o0 = blockIdx.y * BN;

    f32x4 acc[4][4] = {};

    for (int k0 = 0; k0 < HID; k0 += BKE) {
        // stage A,B tiles: 1024 x 16B chunks each; inverse-swizzled global source,
        // linear LDS dest (global_load_lds writes base + lane*16)
#pragma unroll
        for (int it = 0; it < 4; ++it) {
            int off16 = it * 256 + tid;
            int offb  = off16 << 4;
            int loffb = offb ^ (((offb >> 7) & 7) << 4);
            int row = loffb >> 7;            // 0..127
            int kel = (loffb & 127) >> 1;    // 0..63, multiple of 8
            int ldsbyte = ((it * 256) + (wid * 64)) << 4;  // wave-uniform base
            gload_lds16(h1 + (size_t)(b0 + row) * HID + k0 + kel, (char*)As + ldsbyte);
            gload_lds16(w2 + (size_t)(o0 + row) * HID + k0 + kel, (char*)Bs + ldsbyte);
        }
        __syncthreads();

#pragma unroll
        for (int ks = 0; ks < 2; ++ks) {
            short8 af[4], bfr[4];
            int kbyte = ks * 64 + kg * 16;
#pragma unroll
            for (int m = 0; m < 4; ++m) {
                int row = wm * 64 + m * 16 + lr;
                int a = ((row << 7) + kbyte) ^ ((row & 7) << 4);
                af[m] = *(const short8*)((const char*)As + a);
            }
#pragma unroll
            for (int n = 0; n < 4; ++n) {
                int col = wn * 64 + n * 16 + lr;
                int a = ((col << 7) + kbyte) ^ ((col & 7) << 4);
                bfr[n] = *(const short8*)((const char*)Bs + a);
            }
#pragma unroll
            for (int m = 0; m < 4; ++m)
#pragma unroll
                for (int n = 0; n < 4; ++n)
                    acc[m][n] = __builtin_amdgcn_mfma_f32_16x16x32_bf16(
                        af[m], bfr[n], acc[m][n], 0, 0, 0);
        }
        __syncthreads();
    }

    // epilogue: bias + relu, bf16 store. C/D layout: col=lane&15, row=(lane>>4)*4+r
#pragma unroll
    for (int n = 0; n < 4; ++n) {
        int col = o0 + wn * 64 + n * 16 + lr;
        float bias = b2[col];
#pragma unroll
        for (int m = 0; m < 4; ++m) {
            int rbase = b0 + wm * 64 + m * 16 + (lane >> 4) * 4;
#pragma unroll
            for (int r = 0; r < 4; ++r) {
                float v = fmaxf(acc[m][n][r] + bias, 0.f);
                h2[(size_t)(rbase + r) * HID + col] = f2bf(v);
            }
        }
    }
}

// ---------------- heads: action/value from bf16 h2, one wave per sample ----------------
__global__ __launch_bounds__(256) void k_heads(
    const unsigned short* __restrict__ h2, const float* __restrict__ aw,
    const float* __restrict__ ab, const float* __restrict__ vw,
    const float* __restrict__ vb, float* __restrict__ out)
{
    int wave = threadIdx.x >> 6;
    int lane = threadIdx.x & 63;
    int s = blockIdx.x * 4 + wave;

    const unsigned short* hr = h2 + (size_t)s * HID + lane * 8;
    u16x8 hu = *(const u16x8*)hr;
    float hv[8];
#pragma unroll
    for (int j = 0; j < 8; j++) hv[j] = bf2f(hu[j]);

    float part[5];
#pragma unroll
    for (int m = 0; m < 5; m++) {
        const float* wrow = ((m < 4) ? (aw + (size_t)m * HID) : vw) + lane * 8;
        float4 wa = *(const float4*)wrow;
        float4 wb = *(const float4*)(wrow + 4);
        float p = hv[0] * wa.x;
        p = fmaf(hv[1], wa.y, p);
        p = fmaf(hv[2], wa.z, p);
        p = fmaf(hv[3], wa.w, p);
        p = fmaf(hv[4], wb.x, p);
        p = fmaf(hv[5], wb.y, p);
        p = fmaf(hv[6], wb.z, p);
        p = fmaf(hv[7], wb.w, p);
        part[m] = p;
    }
#pragma unroll
    for (int m = 0; m < 5; m++) {
        float v = part[m];
#pragma unroll
        for (int off = 32; off > 0; off >>= 1) v += __shfl_xor(v, off);
        if (lane == 0) {
            if (m < 4) out[(size_t)s * 4 + m] = v + ab[m];
            else       out[(size_t)BB * 4 + s] = v + vb[0];
        }
    }
}

extern "C" void kernel_launch(void* const* d_in, const int* in_sizes, int n_in,
                              void* d_out, int out_size, void* d_ws, size_t ws_size,
                              hipStream_t stream)
{
    const float* x    = (const float*)d_in[0];
    const float* T    = (const float*)d_in[1];
    const float* K    = (const float*)d_in[2];
    const float* l1w  = (const float*)d_in[3];
    const float* l1b  = (const float*)d_in[4];
    const float* l2w  = (const float*)d_in[5];
    const float* l2b  = (const float*)d_in[6];
    const float* actw = (const float*)d_in[7];
    const float* actb = (const float*)d_in[8];
    const float* valw = (const float*)d_in[9];
    const float* valb = (const float*)d_in[10];
    float* out = (float*)d_out;

    char* ws = (char*)d_ws;
    float*          h0  = (float*)ws;                                   // B*40 f32   = 5,242,880 B
    unsigned short* h1  = (unsigned short*)(ws + 5242880);              // B*512 bf16 = 33,554,432 B
    unsigned short* h2  = (unsigned short*)(ws + 5242880 + 33554432);   // B*512 bf16
    unsigned short* w2b = (unsigned short*)(ws + 5242880 + 2*33554432); // 512*512 bf16

    k_cvt   <<<HID * HID / 4 / 256, 256, 0, stream>>>(l2w, w2b);
    k_encode<<<BB * LLV / 256, 256, 0, stream>>>(x, T, K, h0);
    k_gemm1 <<<dim3(2, BB / MB1), 256, 0, stream>>>(h0, l1w, l1b, h1);
    k_gemm2m<<<dim3(BB / BM, HID / BN), 256, 0, stream>>>(h1, w2b, l2b, h2);
    k_heads <<<BB / 4, 256, 0, stream>>>(h2, actw, actb, valw, valb, out);
}

// Round 3
// 119.871 us; speedup vs baseline: 2.9707x; 1.4670x over previous
//
#include <hip/hip_runtime.h>
#include <cstdint>
#include <cstddef>

#define BB   32768
#define DD   8
#define LLV  16
#define TBL  524288
#define HID  512

typedef __attribute__((ext_vector_type(8))) short short8;
typedef __attribute__((ext_vector_type(8))) unsigned short u16x8;
typedef __attribute__((ext_vector_type(4))) float f32x4;

// primes mod 2^32
__device__ __constant__ uint32_t PR[8] = {
    2654436881u, 1620619981u, 1500450271u, 3267000013u,
    1459886047u, 4093082899u,  986956175u, 3628273133u
};

__device__ __forceinline__ unsigned short f2bf(float f) {
    uint32_t u = __float_as_uint(f);
    uint32_t r = (u + 0x7fffu + ((u >> 16) & 1u)) >> 16;   // RNE
    return (unsigned short)r;
}
__device__ __forceinline__ float bf2f(unsigned short u) {
    return __uint_as_float(((uint32_t)u) << 16);
}

__device__ __forceinline__ void gload_lds16(const void* gsrc, void* ldst) {
    __builtin_amdgcn_global_load_lds(
        (const __attribute__((address_space(1))) unsigned int*)gsrc,
        (__attribute__((address_space(3))) unsigned int*)ldst,
        16, 0, 0);
}

// ---------------- encoding: level-major, one thread per b, one level per block ----
// 2048 blocks: block i -> level (i&7) + 8*(i>>10), sample chunk ((i&1023)>>3).
// Default dispatch round-robins XCDs (xcd = i%8), so level l lives on XCD l%8:
// each XCD's L2 sees only 2 of 16 level-tables (8 MB) instead of all 64 MB.
__global__ __launch_bounds__(256) void k_encode(
    const float* __restrict__ x, const float* __restrict__ T,
    const float* __restrict__ Karr, float* __restrict__ h0T)
{
    int i = blockIdx.x;
    int l = (i & 7) + ((i >> 10) << 3);
    int b = ((i & 1023) >> 3) * 256 + threadIdx.x;

    const float4 x0 = *(const float4*)(x + (size_t)b * DD);
    const float4 x1 = *(const float4*)(x + (size_t)b * DD + 4);
    float xs[8] = {x0.x, x0.y, x0.z, x0.w, x1.x, x1.y, x1.z, x1.w};

    float Kl = Karr[l];
    const float* Tl = T + ((size_t)l * TBL) * 2;

    float fr[8];
    int   base[8];
    float cs = 0.f;
#pragma unroll
    for (int i2 = 0; i2 < 8; i2++) {
        cs += xs[i2];                 // sequential fp32 cumsum (matches np)
        float p = cs * Kl;
        fr[i2]   = p - truncf(p);     // trunc-fractional
        base[i2] = (int)floorf(p);    // floor for lattice base
    }

    float c[8];
#pragma unroll
    for (int i2 = 0; i2 < 8; i2++) c[i2] = fr[i2];
#define CE(a_, b_) { float lo_ = fminf(c[a_], c[b_]); float hi_ = fmaxf(c[a_], c[b_]); c[a_] = lo_; c[b_] = hi_; }
    CE(0,1) CE(2,3) CE(4,5) CE(6,7)
    CE(0,2) CE(1,3) CE(4,6) CE(5,7)
    CE(1,2) CE(5,6) CE(0,4) CE(3,7)
    CE(1,5) CE(2,6)
    CE(1,4) CE(3,6)
    CE(2,4) CE(3,5)
    CE(3,4)
#undef CE

    // compute all 9 vertex indices + weights first, then gather (loads overlap)
    uint32_t idx9[9];
    float    w9[9];
    float prevc = 0.f;
#pragma unroll
    for (int j = 0; j < 9; j++) {
        float cj = (j < 8) ? c[j] : 1.0f;
        uint32_t h = 0;
        int prev = 0;
#pragma unroll
        for (int i2 = 0; i2 < 8; i2++) {
            int ai = base[i2] + (fr[i2] >= cj ? 1 : 0);
            h ^= (uint32_t)(ai - prev) * PR[i2];
            prev = ai;
        }
        idx9[j] = h & (TBL - 1);
        w9[j]   = cj - prevc;
        prevc   = cj;
    }

    float f0 = 0.f, f1 = 0.f;
#pragma unroll
    for (int j = 0; j < 9; j++) {
        const float2 tv = *(const float2*)(Tl + ((size_t)idx9[j] << 1));
        f0 = fmaf(tv.x, w9[j], f0);
        f1 = fmaf(tv.y, w9[j], f1);
    }
    f0 /= Kl;
    f1 /= Kl;

    // transposed planes: fully coalesced 4B stores
    h0T[(size_t)(l * 2 + 0) * BB + b] = f0;
    h0T[(size_t)(l * 2 + 1) * BB + b] = f1;
}

// ---------------- gemm1: h1 = relu([x|f] @ W1^T + b1) -> bf16 ----------------
#define MB1 128
__global__ __launch_bounds__(256) void k_gemm1(
    const float* __restrict__ x, const float* __restrict__ h0T,
    const float* __restrict__ w1, const float* __restrict__ b1,
    unsigned short* __restrict__ h1)
{
    __shared__ float sh[MB1 * 40];
    int o  = blockIdx.x * 256 + threadIdx.x;   // output index 0..511
    int b0 = blockIdx.y * MB1;

    float wr[40];
#pragma unroll
    for (int k = 0; k < 40; k += 4) {
        float4 v = *(const float4*)(w1 + (size_t)o * 40 + k);
        wr[k+0] = v.x; wr[k+1] = v.y; wr[k+2] = v.z; wr[k+3] = v.w;
    }
    float bias = b1[o];

    // stage x: 128 rows x 8 floats
    {
        int row = threadIdx.x >> 1, q = threadIdx.x & 1;
        float4 v = *(const float4*)(x + (size_t)(b0 + row) * 8 + q * 4);
        sh[row * 40 + q * 4 + 0] = v.x;
        sh[row * 40 + q * 4 + 1] = v.y;
        sh[row * 40 + q * 4 + 2] = v.z;
        sh[row * 40 + q * 4 + 3] = v.w;
    }
    // stage 32 feature planes x 128 samples
#pragma unroll
    for (int j = 0; j < 4; j++) {
        int t = threadIdx.x + j * 256;
        int plane = t >> 5;          // 0..31 == (l*2+ch)
        int pos   = (t & 31) * 4;    // 0..124
        float4 v = *(const float4*)(h0T + (size_t)plane * BB + b0 + pos);
        sh[(pos + 0) * 40 + 8 + plane] = v.x;
        sh[(pos + 1) * 40 + 8 + plane] = v.y;
        sh[(pos + 2) * 40 + 8 + plane] = v.z;
        sh[(pos + 3) * 40 + 8 + plane] = v.w;
    }
    __syncthreads();

    for (int s = 0; s < MB1; s++) {
        float acc = bias;
#pragma unroll
        for (int k4 = 0; k4 < 10; k4++) {
            float4 hv = *(float4*)&sh[s * 40 + k4 * 4];
            acc = fmaf(wr[k4*4+0], hv.x, acc);
            acc = fmaf(wr[k4*4+1], hv.y, acc);
            acc = fmaf(wr[k4*4+2], hv.z, acc);
            acc = fmaf(wr[k4*4+3], hv.w, acc);
        }
        h1[(size_t)(b0 + s) * HID + o] = f2bf(fmaxf(acc, 0.f));
    }
}

// ---------------- w2 fp32 -> bf16 ----------------
__global__ __launch_bounds__(256) void k_cvt(
    const float* __restrict__ w, unsigned short* __restrict__ o)
{
    int i = blockIdx.x * 256 + threadIdx.x;     // each converts 4
    float4 v = *(const float4*)(w + (size_t)i * 4);
    ushort4 r;
    r.x = f2bf(v.x); r.y = f2bf(v.y); r.z = f2bf(v.z); r.w = f2bf(v.w);
    *(ushort4*)(o + (size_t)i * 4) = r;
}

// ---------------- gemm2: bf16 MFMA 128x128 tile, XOR-swizzled LDS ----------------
#define BM 128
#define BN 128
#define BKE 64

__global__ __launch_bounds__(256) void k_gemm2m(
    const unsigned short* __restrict__ h1, const unsigned short* __restrict__ w2,
    const float* __restrict__ b2, unsigned short* __restrict__ h2)
{
    __shared__ unsigned short As[BM * BKE];   // physical (swizzled) layout
    __shared__ unsigned short Bs[BN * BKE];

    const int tid  = threadIdx.x;
    const int wid  = tid >> 6;
    const int lane = tid & 63;
    const int wm = wid >> 1, wn = wid & 1;
    const int lr = lane & 15;
    const int kg = lane >> 4;

    const int b0 = blockIdx.x * BM;
    const int o0 = blockIdx.y * BN;

    f32x4 acc[4][4] = {};

    for (int k0 = 0; k0 < HID; k0 += BKE) {
#pragma unroll
        for (int it = 0; it < 4; ++it) {
            int off16 = it * 256 + tid;
            int offb  = off16 << 4;
            int loffb = offb ^ (((offb >> 7) & 7) << 4);
            int row = loffb >> 7;            // 0..127
            int kel = (loffb & 127) >> 1;    // 0..63, multiple of 8
            int ldsbyte = ((it * 256) + (wid * 64)) << 4;  // wave-uniform base
            gload_lds16(h1 + (size_t)(b0 + row) * HID + k0 + kel, (char*)As + ldsbyte);
            gload_lds16(w2 + (size_t)(o0 + row) * HID + k0 + kel, (char*)Bs + ldsbyte);
        }
        __syncthreads();

#pragma unroll
        for (int ks = 0; ks < 2; ++ks) {
            short8 af[4], bfr[4];
            int kbyte = ks * 64 + kg * 16;
#pragma unroll
            for (int m = 0; m < 4; ++m) {
                int row = wm * 64 + m * 16 + lr;
                int a = ((row << 7) + kbyte) ^ ((row & 7) << 4);
                af[m] = *(const short8*)((const char*)As + a);
            }
#pragma unroll
            for (int n = 0; n < 4; ++n) {
                int col = wn * 64 + n * 16 + lr;
                int a = ((col << 7) + kbyte) ^ ((col & 7) << 4);
                bfr[n] = *(const short8*)((const char*)Bs + a);
            }
#pragma unroll
            for (int m = 0; m < 4; ++m)
#pragma unroll
                for (int n = 0; n < 4; ++n)
                    acc[m][n] = __builtin_amdgcn_mfma_f32_16x16x32_bf16(
                        af[m], bfr[n], acc[m][n], 0, 0, 0);
        }
        __syncthreads();
    }

    // epilogue: bias + relu, bf16 store. C/D layout: col=lane&15, row=(lane>>4)*4+r
#pragma unroll
    for (int n = 0; n < 4; ++n) {
        int col = o0 + wn * 64 + n * 16 + lr;
        float bias = b2[col];
#pragma unroll
        for (int m = 0; m < 4; ++m) {
            int rbase = b0 + wm * 64 + m * 16 + (lane >> 4) * 4;
#pragma unroll
            for (int r = 0; r < 4; ++r) {
                float v = fmaxf(acc[m][n][r] + bias, 0.f);
                h2[(size_t)(rbase + r) * HID + col] = f2bf(v);
            }
        }
    }
}

// ---------------- heads: action/value from bf16 h2, one wave per sample ----------------
__global__ __launch_bounds__(256) void k_heads(
    const unsigned short* __restrict__ h2, const float* __restrict__ aw,
    const float* __restrict__ ab, const float* __restrict__ vw,
    const float* __restrict__ vb, float* __restrict__ out)
{
    int wave = threadIdx.x >> 6;
    int lane = threadIdx.x & 63;
    int s = blockIdx.x * 4 + wave;

    const unsigned short* hr = h2 + (size_t)s * HID + lane * 8;
    u16x8 hu = *(const u16x8*)hr;
    float hv[8];
#pragma unroll
    for (int j = 0; j < 8; j++) hv[j] = bf2f(hu[j]);

    float part[5];
#pragma unroll
    for (int m = 0; m < 5; m++) {
        const float* wrow = ((m < 4) ? (aw + (size_t)m * HID) : vw) + lane * 8;
        float4 wa = *(const float4*)wrow;
        float4 wb = *(const float4*)(wrow + 4);
        float p = hv[0] * wa.x;
        p = fmaf(hv[1], wa.y, p);
        p = fmaf(hv[2], wa.z, p);
        p = fmaf(hv[3], wa.w, p);
        p = fmaf(hv[4], wb.x, p);
        p = fmaf(hv[5], wb.y, p);
        p = fmaf(hv[6], wb.z, p);
        p = fmaf(hv[7], wb.w, p);
        part[m] = p;
    }
#pragma unroll
    for (int m = 0; m < 5; m++) {
        float v = part[m];
#pragma unroll
        for (int off = 32; off > 0; off >>= 1) v += __shfl_xor(v, off);
        if (lane == 0) {
            if (m < 4) out[(size_t)s * 4 + m] = v + ab[m];
            else       out[(size_t)BB * 4 + s] = v + vb[0];
        }
    }
}

extern "C" void kernel_launch(void* const* d_in, const int* in_sizes, int n_in,
                              void* d_out, int out_size, void* d_ws, size_t ws_size,
                              hipStream_t stream)
{
    const float* x    = (const float*)d_in[0];
    const float* T    = (const float*)d_in[1];
    const float* K    = (const float*)d_in[2];
    const float* l1w  = (const float*)d_in[3];
    const float* l1b  = (const float*)d_in[4];
    const float* l2w  = (const float*)d_in[5];
    const float* l2b  = (const float*)d_in[6];
    const float* actw = (const float*)d_in[7];
    const float* actb = (const float*)d_in[8];
    const float* valw = (const float*)d_in[9];
    const float* valb = (const float*)d_in[10];
    float* out = (float*)d_out;

    char* ws = (char*)d_ws;
    float*          h0T = (float*)ws;                                   // 32*B f32   = 4,194,304 B
    unsigned short* h1  = (unsigned short*)(ws + 4194304);              // B*512 bf16 = 33,554,432 B
    unsigned short* h2  = (unsigned short*)(ws + 4194304 + 33554432);   // B*512 bf16
    unsigned short* w2b = (unsigned short*)(ws + 4194304 + 2*33554432); // 512*512 bf16

    k_cvt   <<<HID * HID / 4 / 256, 256, 0, stream>>>(l2w, w2b);
    k_encode<<<2048, 256, 0, stream>>>(x, T, K, h0T);
    k_gemm1 <<<dim3(2, BB / MB1), 256, 0, stream>>>(x, h0T, l1w, l1b, h1);
    k_gemm2m<<<dim3(BB / BM, HID / BN), 256, 0, stream>>>(h1, w2b, l2b, h2);
    k_heads <<<BB / 4, 256, 0, stream>>>(h2, actw, actb, valw, valb, out);
}

// Round 4
// 95.490 us; speedup vs baseline: 3.7292x; 1.2553x over previous
//
#include <hip/hip_runtime.h>
#include <cstdint>
#include <cstddef>

#define BB   32768
#define DD   8
#define LLV  16
#define TBL  524288
#define HID  512

typedef __attribute__((ext_vector_type(8))) short short8;
typedef __attribute__((ext_vector_type(8))) unsigned short u16x8;
typedef __attribute__((ext_vector_type(4))) float f32x4;

// primes mod 2^32
__device__ __constant__ uint32_t PR[8] = {
    2654436881u, 1620619981u, 1500450271u, 3267000013u,
    1459886047u, 4093082899u,  986956175u, 3628273133u
};

__device__ __forceinline__ unsigned short f2bf(float f) {
    uint32_t u = __float_as_uint(f);
    uint32_t r = (u + 0x7fffu + ((u >> 16) & 1u)) >> 16;   // RNE
    return (unsigned short)r;
}
__device__ __forceinline__ float bf2f(unsigned short u) {
    return __uint_as_float(((uint32_t)u) << 16);
}

__device__ __forceinline__ void gload_lds16(const void* gsrc, void* ldst) {
    __builtin_amdgcn_global_load_lds(
        (const __attribute__((address_space(1))) unsigned int*)gsrc,
        (__attribute__((address_space(3))) unsigned int*)ldst,
        16, 0, 0);
}

// ---------------- encoding: level-major, one thread per b, one level per block ----
// block i -> level (i&7)+8*(i>>10); xcd = i%8 so each XCD L2 holds 2 level-tables.
__global__ __launch_bounds__(256) void k_encode(
    const float* __restrict__ x, const float* __restrict__ T,
    const float* __restrict__ Karr, unsigned short* __restrict__ h0T)
{
    int i = blockIdx.x;
    int l = (i & 7) + ((i >> 10) << 3);
    int b = ((i & 1023) >> 3) * 256 + threadIdx.x;

    const float4 x0 = *(const float4*)(x + (size_t)b * DD);
    const float4 x1 = *(const float4*)(x + (size_t)b * DD + 4);
    float xs[8] = {x0.x, x0.y, x0.z, x0.w, x1.x, x1.y, x1.z, x1.w};

    float Kl = Karr[l];
    const float* Tl = T + ((size_t)l * TBL) * 2;

    float fr[8];
    int   base[8];
    float cs = 0.f;
#pragma unroll
    for (int i2 = 0; i2 < 8; i2++) {
        cs += xs[i2];                 // sequential fp32 cumsum (matches np)
        float p = cs * Kl;
        fr[i2]   = p - truncf(p);
        base[i2] = (int)floorf(p);
    }

    float c[8];
#pragma unroll
    for (int i2 = 0; i2 < 8; i2++) c[i2] = fr[i2];
#define CE(a_, b_) { float lo_ = fminf(c[a_], c[b_]); float hi_ = fmaxf(c[a_], c[b_]); c[a_] = lo_; c[b_] = hi_; }
    CE(0,1) CE(2,3) CE(4,5) CE(6,7)
    CE(0,2) CE(1,3) CE(4,6) CE(5,7)
    CE(1,2) CE(5,6) CE(0,4) CE(3,7)
    CE(1,5) CE(2,6)
    CE(1,4) CE(3,6)
    CE(2,4) CE(3,5)
    CE(3,4)
#undef CE

    uint32_t idx9[9];
    float    w9[9];
    float prevc = 0.f;
#pragma unroll
    for (int j = 0; j < 9; j++) {
        float cj = (j < 8) ? c[j] : 1.0f;
        uint32_t h = 0;
        int prev = 0;
#pragma unroll
        for (int i2 = 0; i2 < 8; i2++) {
            int ai = base[i2] + (fr[i2] >= cj ? 1 : 0);
            h ^= (uint32_t)(ai - prev) * PR[i2];
            prev = ai;
        }
        idx9[j] = h & (TBL - 1);
        w9[j]   = cj - prevc;
        prevc   = cj;
    }

    float f0 = 0.f, f1 = 0.f;
#pragma unroll
    for (int j = 0; j < 9; j++) {
        const float2 tv = *(const float2*)(Tl + ((size_t)idx9[j] << 1));
        f0 = fmaf(tv.x, w9[j], f0);
        f1 = fmaf(tv.y, w9[j], f1);
    }
    f0 /= Kl;
    f1 /= Kl;

    // bf16 plane stores, coalesced
    h0T[(size_t)(l * 2 + 0) * BB + b] = f2bf(f0);
    h0T[(size_t)(l * 2 + 1) * BB + b] = f2bf(f1);
}

// ---------------- pack: planes + x -> row-major bf16 [B][64] (zero-padded K) ----
__global__ __launch_bounds__(256) void k_pack(
    const unsigned short* __restrict__ h0T, const float* __restrict__ x,
    unsigned short* __restrict__ h0b)
{
    int b = blockIdx.x * 256 + threadIdx.x;
    unsigned short row[64];
    const float4 x0 = *(const float4*)(x + (size_t)b * 8);
    const float4 x1 = *(const float4*)(x + (size_t)b * 8 + 4);
    row[0] = f2bf(x0.x); row[1] = f2bf(x0.y); row[2] = f2bf(x0.z); row[3] = f2bf(x0.w);
    row[4] = f2bf(x1.x); row[5] = f2bf(x1.y); row[6] = f2bf(x1.z); row[7] = f2bf(x1.w);
#pragma unroll
    for (int p = 0; p < 32; p++) row[8 + p] = h0T[(size_t)p * BB + b];
#pragma unroll
    for (int c = 40; c < 64; c++) row[c] = 0;
#pragma unroll
    for (int i = 0; i < 8; i++)
        *(u16x8*)(h0b + (size_t)b * 64 + i * 8) = *(u16x8*)(row + i * 8);
}

// ---------------- weight converts ----------------
__global__ __launch_bounds__(256) void k_cvt(
    const float* __restrict__ w, unsigned short* __restrict__ o)
{
    int i = blockIdx.x * 256 + threadIdx.x;     // each converts 4
    float4 v = *(const float4*)(w + (size_t)i * 4);
    ushort4 r;
    r.x = f2bf(v.x); r.y = f2bf(v.y); r.z = f2bf(v.z); r.w = f2bf(v.w);
    *(ushort4*)(o + (size_t)i * 4) = r;
}

__global__ __launch_bounds__(256) void k_cvt1(
    const float* __restrict__ w, unsigned short* __restrict__ o)  // [512][40] -> [512][64] pad
{
    int i = blockIdx.x * 256 + threadIdx.x;     // 8192 threads
    int row = i >> 4, c4 = (i & 15) * 4;
    ushort4 r = make_ushort4(0, 0, 0, 0);
    if (c4 < 40) {
        float4 v = *(const float4*)(w + (size_t)row * 40 + c4);
        r.x = f2bf(v.x); r.y = f2bf(v.y); r.z = f2bf(v.z); r.w = f2bf(v.w);
    }
    *(ushort4*)(o + (size_t)row * 64 + c4) = r;
}

// ------- unified bf16 MFMA GEMM: Out[M][512] = relu(A[M][K] @ Bw[512][K]^T + bias) -------
template<int KK>
__global__ __launch_bounds__(256) void k_mgemm(
    const unsigned short* __restrict__ A, const unsigned short* __restrict__ Bw,
    const float* __restrict__ bias, unsigned short* __restrict__ Out)
{
    __shared__ unsigned short As[128 * 64];   // physical (swizzled) layout
    __shared__ unsigned short Bs[128 * 64];

    const int tid  = threadIdx.x;
    const int wid  = tid >> 6;
    const int lane = tid & 63;
    const int wm = wid >> 1, wn = wid & 1;
    const int lr = lane & 15;
    const int kg = lane >> 4;

    const int b0 = blockIdx.x * 128;
    const int o0 = blockIdx.y * 128;

    f32x4 acc[4][4] = {};

    for (int k0 = 0; k0 < KK; k0 += 64) {
        // stage A,B tiles: inverse-swizzled global source, linear LDS dest
#pragma unroll
        for (int it = 0; it < 4; ++it) {
            int offb  = (it * 256 + tid) << 4;
            int loffb = offb ^ (((offb >> 7) & 7) << 4);
            int row = loffb >> 7;            // 0..127
            int kel = (loffb & 127) >> 1;    // 0..63, multiple of 8
            int ldsbyte = ((it * 256) + (wid * 64)) << 4;  // wave-uniform base
            gload_lds16(A  + (size_t)(b0 + row) * KK + k0 + kel, (char*)As + ldsbyte);
            gload_lds16(Bw + (size_t)(o0 + row) * KK + k0 + kel, (char*)Bs + ldsbyte);
        }
        __syncthreads();

#pragma unroll
        for (int ks = 0; ks < 2; ++ks) {
            short8 af[4], bfr[4];
            int kbyte = ks * 64 + kg * 16;
#pragma unroll
            for (int m = 0; m < 4; ++m) {
                int row = wm * 64 + m * 16 + lr;
                int a = ((row << 7) + kbyte) ^ ((row & 7) << 4);
                af[m] = *(const short8*)((const char*)As + a);
            }
#pragma unroll
            for (int n = 0; n < 4; ++n) {
                int col = wn * 64 + n * 16 + lr;
                int a = ((col << 7) + kbyte) ^ ((col & 7) << 4);
                bfr[n] = *(const short8*)((const char*)Bs + a);
            }
#pragma unroll
            for (int m = 0; m < 4; ++m)
#pragma unroll
                for (int n = 0; n < 4; ++n)
                    acc[m][n] = __builtin_amdgcn_mfma_f32_16x16x32_bf16(
                        af[m], bfr[n], acc[m][n], 0, 0, 0);
        }
        __syncthreads();
    }

    // epilogue: bias + relu, bf16 store. C/D layout: col=lane&15, row=(lane>>4)*4+r
#pragma unroll
    for (int n = 0; n < 4; ++n) {
        int col = o0 + wn * 64 + n * 16 + lr;
        float bv = bias[col];
#pragma unroll
        for (int m = 0; m < 4; ++m) {
            int rbase = b0 + wm * 64 + m * 16 + (lane >> 4) * 4;
#pragma unroll
            for (int r = 0; r < 4; ++r) {
                float v = fmaxf(acc[m][n][r] + bv, 0.f);
                Out[(size_t)(rbase + r) * HID + col] = f2bf(v);
            }
        }
    }
}

// ---------------- heads: action/value from bf16 h2, one wave per sample ----------------
__global__ __launch_bounds__(256) void k_heads(
    const unsigned short* __restrict__ h2, const float* __restrict__ aw,
    const float* __restrict__ ab, const float* __restrict__ vw,
    const float* __restrict__ vb, float* __restrict__ out)
{
    int wave = threadIdx.x >> 6;
    int lane = threadIdx.x & 63;
    int s = blockIdx.x * 4 + wave;

    const unsigned short* hr = h2 + (size_t)s * HID + lane * 8;
    u16x8 hu = *(const u16x8*)hr;
    float hv[8];
#pragma unroll
    for (int j = 0; j < 8; j++) hv[j] = bf2f(hu[j]);

    float part[5];
#pragma unroll
    for (int m = 0; m < 5; m++) {
        const float* wrow = ((m < 4) ? (aw + (size_t)m * HID) : vw) + lane * 8;
        float4 wa = *(const float4*)wrow;
        float4 wb = *(const float4*)(wrow + 4);
        float p = hv[0] * wa.x;
        p = fmaf(hv[1], wa.y, p);
        p = fmaf(hv[2], wa.z, p);
        p = fmaf(hv[3], wa.w, p);
        p = fmaf(hv[4], wb.x, p);
        p = fmaf(hv[5], wb.y, p);
        p = fmaf(hv[6], wb.z, p);
        p = fmaf(hv[7], wb.w, p);
        part[m] = p;
    }
#pragma unroll
    for (int m = 0; m < 5; m++) {
        float v = part[m];
#pragma unroll
        for (int off = 32; off > 0; off >>= 1) v += __shfl_xor(v, off);
        if (lane == 0) {
            if (m < 4) out[(size_t)s * 4 + m] = v + ab[m];
            else       out[(size_t)BB * 4 + s] = v + vb[0];
        }
    }
}

extern "C" void kernel_launch(void* const* d_in, const int* in_sizes, int n_in,
                              void* d_out, int out_size, void* d_ws, size_t ws_size,
                              hipStream_t stream)
{
    const float* x    = (const float*)d_in[0];
    const float* T    = (const float*)d_in[1];
    const float* K    = (const float*)d_in[2];
    const float* l1w  = (const float*)d_in[3];
    const float* l1b  = (const float*)d_in[4];
    const float* l2w  = (const float*)d_in[5];
    const float* l2b  = (const float*)d_in[6];
    const float* actw = (const float*)d_in[7];
    const float* actb = (const float*)d_in[8];
    const float* valw = (const float*)d_in[9];
    const float* valb = (const float*)d_in[10];
    float* out = (float*)d_out;

    char* ws = (char*)d_ws;
    unsigned short* h0b = (unsigned short*)ws;                    // B*64 bf16  = 4,194,304 B
    unsigned short* h1  = (unsigned short*)(ws + 4194304);        // B*512 bf16 = 33,554,432 B
    unsigned short* h2  = (unsigned short*)(ws + 37748736);       // B*512 bf16 = 33,554,432 B
    unsigned short* w2b = (unsigned short*)(ws + 71303168);       // 512*512 bf16 = 524,288 B
    unsigned short* w1b = (unsigned short*)(ws + 71827456);       // 512*64 bf16  = 65,536 B
    // h0T planes alias the h2 region: consumed by k_pack before k_mgemm<512> writes h2
    unsigned short* h0T = h2;                                     // 32*B bf16 = 2,097,152 B

    k_cvt       <<<HID * HID / 4 / 256, 256, 0, stream>>>(l2w, w2b);
    k_cvt1      <<<32, 256, 0, stream>>>(l1w, w1b);
    k_encode    <<<2048, 256, 0, stream>>>(x, T, K, h0T);
    k_pack      <<<BB / 256, 256, 0, stream>>>(h0T, x, h0b);
    k_mgemm<64> <<<dim3(BB / 128, 4), 256, 0, stream>>>(h0b, w1b, l1b, h1);
    k_mgemm<512><<<dim3(BB / 128, 4), 256, 0, stream>>>(h1, w2b, l2b, h2);
    k_heads     <<<BB / 4, 256, 0, stream>>>(h2, actw, actb, valw, valb, out);
}

// Round 5
// 94.493 us; speedup vs baseline: 3.7685x; 1.0106x over previous
//
#include <hip/hip_runtime.h>
#include <cstdint>
#include <cstddef>

#define BB   32768
#define DD   8
#define LLV  16
#define TBL  524288
#define HID  512

typedef __attribute__((ext_vector_type(8))) short short8;
typedef __attribute__((ext_vector_type(8))) unsigned short u16x8;
typedef __attribute__((ext_vector_type(4))) float f32x4;

// primes mod 2^32
__device__ __constant__ uint32_t PR[8] = {
    2654436881u, 1620619981u, 1500450271u, 3267000013u,
    1459886047u, 4093082899u,  986956175u, 3628273133u
};

__device__ __forceinline__ unsigned short f2bf(float f) {
    uint32_t u = __float_as_uint(f);
    uint32_t r = (u + 0x7fffu + ((u >> 16) & 1u)) >> 16;   // RNE
    return (unsigned short)r;
}
__device__ __forceinline__ float bf2f(unsigned short u) {
    return __uint_as_float(((uint32_t)u) << 16);
}

__device__ __forceinline__ void gload_lds16(const void* gsrc, void* ldst) {
    __builtin_amdgcn_global_load_lds(
        (const __attribute__((address_space(1))) unsigned int*)gsrc,
        (__attribute__((address_space(3))) unsigned int*)ldst,
        16, 0, 0);
}

// per-sample: cumsum -> sort -> 9 vertex hashes + weights
__device__ __forceinline__ void enc_idx(const float xs[8], float Kl,
                                        uint32_t idx9[9], float w9[9])
{
    float fr[8];
    int   base[8];
    float cs = 0.f;
#pragma unroll
    for (int i2 = 0; i2 < 8; i2++) {
        cs += xs[i2];                 // sequential fp32 cumsum (matches np)
        float p = cs * Kl;
        fr[i2]   = p - truncf(p);
        base[i2] = (int)floorf(p);
    }

    float c[8];
#pragma unroll
    for (int i2 = 0; i2 < 8; i2++) c[i2] = fr[i2];
#define CE(a_, b_) { float lo_ = fminf(c[a_], c[b_]); float hi_ = fmaxf(c[a_], c[b_]); c[a_] = lo_; c[b_] = hi_; }
    CE(0,1) CE(2,3) CE(4,5) CE(6,7)
    CE(0,2) CE(1,3) CE(4,6) CE(5,7)
    CE(1,2) CE(5,6) CE(0,4) CE(3,7)
    CE(1,5) CE(2,6)
    CE(1,4) CE(3,6)
    CE(2,4) CE(3,5)
    CE(3,4)
#undef CE

    float prevc = 0.f;
#pragma unroll
    for (int j = 0; j < 9; j++) {
        float cj = (j < 8) ? c[j] : 1.0f;
        uint32_t h = 0;
        int prev = 0;
#pragma unroll
        for (int i2 = 0; i2 < 8; i2++) {
            int ai = base[i2] + (fr[i2] >= cj ? 1 : 0);
            h ^= (uint32_t)(ai - prev) * PR[i2];
            prev = ai;
        }
        idx9[j] = h & (TBL - 1);
        w9[j]   = cj - prevc;
        prevc   = cj;
    }
}

// ---------------- encoding: level-major, 2 samples per thread ----------------
// 1024 blocks: block i -> level (i&7)+8*(i>>9); xcd = i%8 so each XCD's L2
// holds one 4 MB level-table per temporal phase. 18 gathers in flight/thread.
__global__ __launch_bounds__(256) void k_encode(
    const float* __restrict__ x, const float* __restrict__ T,
    const float* __restrict__ Karr, unsigned short* __restrict__ h0T)
{
    int i = blockIdx.x;
    int l = (i & 7) + ((i >> 9) << 3);
    int ba = ((i & 511) >> 3) * 512 + threadIdx.x;   // sample A
    int bb = ba + 256;                                // sample B

    float Kl = Karr[l];
    const float* Tl = T + ((size_t)l * TBL) * 2;

    const float4 a0 = *(const float4*)(x + (size_t)ba * DD);
    const float4 a1 = *(const float4*)(x + (size_t)ba * DD + 4);
    const float4 b0 = *(const float4*)(x + (size_t)bb * DD);
    const float4 b1 = *(const float4*)(x + (size_t)bb * DD + 4);
    float xa[8] = {a0.x, a0.y, a0.z, a0.w, a1.x, a1.y, a1.z, a1.w};
    float xb[8] = {b0.x, b0.y, b0.z, b0.w, b1.x, b1.y, b1.z, b1.w};

    uint32_t ia[9], ib[9];
    float    wa[9], wb[9];
    float2   ta[9], tb[9];

    enc_idx(xa, Kl, ia, wa);
#pragma unroll
    for (int j = 0; j < 9; j++) ta[j] = *(const float2*)(Tl + ((size_t)ia[j] << 1));
    __builtin_amdgcn_sched_barrier(0);   // loads A issued before hash B

    enc_idx(xb, Kl, ib, wb);
#pragma unroll
    for (int j = 0; j < 9; j++) tb[j] = *(const float2*)(Tl + ((size_t)ib[j] << 1));
    __builtin_amdgcn_sched_barrier(0);   // all 18 loads in flight before any use

    float fa0 = 0.f, fa1 = 0.f, fb0 = 0.f, fb1 = 0.f;
#pragma unroll
    for (int j = 0; j < 9; j++) {
        fa0 = fmaf(ta[j].x, wa[j], fa0);
        fa1 = fmaf(ta[j].y, wa[j], fa1);
        fb0 = fmaf(tb[j].x, wb[j], fb0);
        fb1 = fmaf(tb[j].y, wb[j], fb1);
    }
    fa0 /= Kl; fa1 /= Kl; fb0 /= Kl; fb1 /= Kl;

    h0T[(size_t)(l * 2 + 0) * BB + ba] = f2bf(fa0);
    h0T[(size_t)(l * 2 + 1) * BB + ba] = f2bf(fa1);
    h0T[(size_t)(l * 2 + 0) * BB + bb] = f2bf(fb0);
    h0T[(size_t)(l * 2 + 1) * BB + bb] = f2bf(fb1);
}

// ---------------- pack: planes + x -> row-major bf16 [B][64] (zero-padded K) ----
__global__ __launch_bounds__(256) void k_pack(
    const unsigned short* __restrict__ h0T, const float* __restrict__ x,
    unsigned short* __restrict__ h0b)
{
    int b = blockIdx.x * 256 + threadIdx.x;
    unsigned short row[64];
    const float4 x0 = *(const float4*)(x + (size_t)b * 8);
    const float4 x1 = *(const float4*)(x + (size_t)b * 8 + 4);
    row[0] = f2bf(x0.x); row[1] = f2bf(x0.y); row[2] = f2bf(x0.z); row[3] = f2bf(x0.w);
    row[4] = f2bf(x1.x); row[5] = f2bf(x1.y); row[6] = f2bf(x1.z); row[7] = f2bf(x1.w);
#pragma unroll
    for (int p = 0; p < 32; p++) row[8 + p] = h0T[(size_t)p * BB + b];
#pragma unroll
    for (int c = 40; c < 64; c++) row[c] = 0;
#pragma unroll
    for (int i = 0; i < 8; i++)
        *(u16x8*)(h0b + (size_t)b * 64 + i * 8) = *(u16x8*)(row + i * 8);
}

// ---------------- weight converts ----------------
__global__ __launch_bounds__(256) void k_cvt(
    const float* __restrict__ w, unsigned short* __restrict__ o)
{
    int i = blockIdx.x * 256 + threadIdx.x;     // each converts 4
    float4 v = *(const float4*)(w + (size_t)i * 4);
    ushort4 r;
    r.x = f2bf(v.x); r.y = f2bf(v.y); r.z = f2bf(v.z); r.w = f2bf(v.w);
    *(ushort4*)(o + (size_t)i * 4) = r;
}

__global__ __launch_bounds__(256) void k_cvt1(
    const float* __restrict__ w, unsigned short* __restrict__ o)  // [512][40] -> [512][64] pad
{
    int i = blockIdx.x * 256 + threadIdx.x;     // 8192 threads
    int row = i >> 4, c4 = (i & 15) * 4;
    ushort4 r = make_ushort4(0, 0, 0, 0);
    if (c4 < 40) {
        float4 v = *(const float4*)(w + (size_t)row * 40 + c4);
        r.x = f2bf(v.x); r.y = f2bf(v.y); r.z = f2bf(v.z); r.w = f2bf(v.w);
    }
    *(ushort4*)(o + (size_t)row * 64 + c4) = r;
}

// ------- unified bf16 MFMA GEMM: Out[M][512] = relu(A[M][K] @ Bw[512][K]^T + bias) -------
template<int KK>
__global__ __launch_bounds__(256) void k_mgemm(
    const unsigned short* __restrict__ A, const unsigned short* __restrict__ Bw,
    const float* __restrict__ bias, unsigned short* __restrict__ Out)
{
    __shared__ unsigned short As[128 * 64];   // physical (swizzled) layout
    __shared__ unsigned short Bs[128 * 64];

    const int tid  = threadIdx.x;
    const int wid  = tid >> 6;
    const int lane = tid & 63;
    const int wm = wid >> 1, wn = wid & 1;
    const int lr = lane & 15;
    const int kg = lane >> 4;

    const int b0 = blockIdx.x * 128;
    const int o0 = blockIdx.y * 128;

    f32x4 acc[4][4] = {};

    for (int k0 = 0; k0 < KK; k0 += 64) {
        // stage A,B tiles: inverse-swizzled global source, linear LDS dest
#pragma unroll
        for (int it = 0; it < 4; ++it) {
            int offb  = (it * 256 + tid) << 4;
            int loffb = offb ^ (((offb >> 7) & 7) << 4);
            int row = loffb >> 7;            // 0..127
            int kel = (loffb & 127) >> 1;    // 0..63, multiple of 8
            int ldsbyte = ((it * 256) + (wid * 64)) << 4;  // wave-uniform base
            gload_lds16(A  + (size_t)(b0 + row) * KK + k0 + kel, (char*)As + ldsbyte);
            gload_lds16(Bw + (size_t)(o0 + row) * KK + k0 + kel, (char*)Bs + ldsbyte);
        }
        __syncthreads();

#pragma unroll
        for (int ks = 0; ks < 2; ++ks) {
            short8 af[4], bfr[4];
            int kbyte = ks * 64 + kg * 16;
#pragma unroll
            for (int m = 0; m < 4; ++m) {
                int row = wm * 64 + m * 16 + lr;
                int a = ((row << 7) + kbyte) ^ ((row & 7) << 4);
                af[m] = *(const short8*)((const char*)As + a);
            }
#pragma unroll
            for (int n = 0; n < 4; ++n) {
                int col = wn * 64 + n * 16 + lr;
                int a = ((col << 7) + kbyte) ^ ((col & 7) << 4);
                bfr[n] = *(const short8*)((const char*)Bs + a);
            }
#pragma unroll
            for (int m = 0; m < 4; ++m)
#pragma unroll
                for (int n = 0; n < 4; ++n)
                    acc[m][n] = __builtin_amdgcn_mfma_f32_16x16x32_bf16(
                        af[m], bfr[n], acc[m][n], 0, 0, 0);
        }
        __syncthreads();
    }

    // epilogue: bias + relu, bf16 store. C/D layout: col=lane&15, row=(lane>>4)*4+r
#pragma unroll
    for (int n = 0; n < 4; ++n) {
        int col = o0 + wn * 64 + n * 16 + lr;
        float bv = bias[col];
#pragma unroll
        for (int m = 0; m < 4; ++m) {
            int rbase = b0 + wm * 64 + m * 16 + (lane >> 4) * 4;
#pragma unroll
            for (int r = 0; r < 4; ++r) {
                float v = fmaxf(acc[m][n][r] + bv, 0.f);
                Out[(size_t)(rbase + r) * HID + col] = f2bf(v);
            }
        }
    }
}

// ---------------- heads: action/value from bf16 h2, one wave per sample ----------------
__global__ __launch_bounds__(256) void k_heads(
    const unsigned short* __restrict__ h2, const float* __restrict__ aw,
    const float* __restrict__ ab, const float* __restrict__ vw,
    const float* __restrict__ vb, float* __restrict__ out)
{
    int wave = threadIdx.x >> 6;
    int lane = threadIdx.x & 63;
    int s = blockIdx.x * 4 + wave;

    const unsigned short* hr = h2 + (size_t)s * HID + lane * 8;
    u16x8 hu = *(const u16x8*)hr;
    float hv[8];
#pragma unroll
    for (int j = 0; j < 8; j++) hv[j] = bf2f(hu[j]);

    float part[5];
#pragma unroll
    for (int m = 0; m < 5; m++) {
        const float* wrow = ((m < 4) ? (aw + (size_t)m * HID) : vw) + lane * 8;
        float4 wa = *(const float4*)wrow;
        float4 wb = *(const float4*)(wrow + 4);
        float p = hv[0] * wa.x;
        p = fmaf(hv[1], wa.y, p);
        p = fmaf(hv[2], wa.z, p);
        p = fmaf(hv[3], wa.w, p);
        p = fmaf(hv[4], wb.x, p);
        p = fmaf(hv[5], wb.y, p);
        p = fmaf(hv[6], wb.z, p);
        p = fmaf(hv[7], wb.w, p);
        part[m] = p;
    }
#pragma unroll
    for (int m = 0; m < 5; m++) {
        float v = part[m];
#pragma unroll
        for (int off = 32; off > 0; off >>= 1) v += __shfl_xor(v, off);
        if (lane == 0) {
            if (m < 4) out[(size_t)s * 4 + m] = v + ab[m];
            else       out[(size_t)BB * 4 + s] = v + vb[0];
        }
    }
}

extern "C" void kernel_launch(void* const* d_in, const int* in_sizes, int n_in,
                              void* d_out, int out_size, void* d_ws, size_t ws_size,
                              hipStream_t stream)
{
    const float* x    = (const float*)d_in[0];
    const float* T    = (const float*)d_in[1];
    const float* K    = (const float*)d_in[2];
    const float* l1w  = (const float*)d_in[3];
    const float* l1b  = (const float*)d_in[4];
    const float* l2w  = (const float*)d_in[5];
    const float* l2b  = (const float*)d_in[6];
    const float* actw = (const float*)d_in[7];
    const float* actb = (const float*)d_in[8];
    const float* valw = (const float*)d_in[9];
    const float* valb = (const float*)d_in[10];
    float* out = (float*)d_out;

    char* ws = (char*)d_ws;
    unsigned short* h0b = (unsigned short*)ws;                    // B*64 bf16  = 4,194,304 B
    unsigned short* h1  = (unsigned short*)(ws + 4194304);        // B*512 bf16 = 33,554,432 B
    unsigned short* h2  = (unsigned short*)(ws + 37748736);       // B*512 bf16 = 33,554,432 B
    unsigned short* w2b = (unsigned short*)(ws + 71303168);       // 512*512 bf16 = 524,288 B
    unsigned short* w1b = (unsigned short*)(ws + 71827456);       // 512*64 bf16  = 65,536 B
    // h0T planes alias the h2 region: consumed by k_pack before k_mgemm<512> writes h2
    unsigned short* h0T = h2;                                     // 32*B bf16 = 2,097,152 B

    k_encode    <<<1024, 256, 0, stream>>>(x, T, K, h0T);
    k_cvt       <<<HID * HID / 4 / 256, 256, 0, stream>>>(l2w, w2b);
    k_cvt1      <<<32, 256, 0, stream>>>(l1w, w1b);
    k_pack      <<<BB / 256, 256, 0, stream>>>(h0T, x, h0b);
    k_mgemm<64> <<<dim3(BB / 128, 4), 256, 0, stream>>>(h0b, w1b, l1b, h1);
    k_mgemm<512><<<dim3(BB / 128, 4), 256, 0, stream>>>(h1, w2b, l2b, h2);
    k_heads     <<<BB / 4, 256, 0, stream>>>(h2, actw, actb, valw, valb, out);
}

// Round 6
// 91.779 us; speedup vs baseline: 3.8799x; 1.0296x over previous
//
#include <hip/hip_runtime.h>
#include <cstdint>
#include <cstddef>

#define BB   32768
#define DD   8
#define LLV  16
#define TBL  524288
#define HID  512

typedef __attribute__((ext_vector_type(8))) short short8;
typedef __attribute__((ext_vector_type(8))) unsigned short u16x8;
typedef __attribute__((ext_vector_type(4))) float f32x4;
typedef __attribute__((ext_vector_type(2))) float f32x2;

// primes mod 2^32
__device__ __constant__ uint32_t PR[8] = {
    2654436881u, 1620619981u, 1500450271u, 3267000013u,
    1459886047u, 4093082899u,  986956175u, 3628273133u
};

__device__ __forceinline__ unsigned short f2bf(float f) {
    uint32_t u = __float_as_uint(f);
    uint32_t r = (u + 0x7fffu + ((u >> 16) & 1u)) >> 16;   // RNE
    return (unsigned short)r;
}
__device__ __forceinline__ float bf2f(unsigned short u) {
    return __uint_as_float(((uint32_t)u) << 16);
}

__device__ __forceinline__ void gload_lds16(const void* gsrc, void* ldst) {
    __builtin_amdgcn_global_load_lds(
        (const __attribute__((address_space(1))) unsigned int*)gsrc,
        (__attribute__((address_space(3))) unsigned int*)ldst,
        16, 0, 0);
}

// per-sample: cumsum -> sort -> 9 vertex hashes + weights
__device__ __forceinline__ void enc_idx(const float xs[8], float Kl,
                                        uint32_t idx9[9], float w9[9])
{
    float fr[8];
    int   base[8];
    float cs = 0.f;
#pragma unroll
    for (int i2 = 0; i2 < 8; i2++) {
        cs += xs[i2];                 // sequential fp32 cumsum (matches np)
        float p = cs * Kl;
        fr[i2]   = p - truncf(p);
        base[i2] = (int)floorf(p);
    }

    float c[8];
#pragma unroll
    for (int i2 = 0; i2 < 8; i2++) c[i2] = fr[i2];
#define CE(a_, b_) { float lo_ = fminf(c[a_], c[b_]); float hi_ = fmaxf(c[a_], c[b_]); c[a_] = lo_; c[b_] = hi_; }
    CE(0,1) CE(2,3) CE(4,5) CE(6,7)
    CE(0,2) CE(1,3) CE(4,6) CE(5,7)
    CE(1,2) CE(5,6) CE(0,4) CE(3,7)
    CE(1,5) CE(2,6)
    CE(1,4) CE(3,6)
    CE(2,4) CE(3,5)
    CE(3,4)
#undef CE

    float prevc = 0.f;
#pragma unroll
    for (int j = 0; j < 9; j++) {
        float cj = (j < 8) ? c[j] : 1.0f;
        uint32_t h = 0;
        int prev = 0;
#pragma unroll
        for (int i2 = 0; i2 < 8; i2++) {
            int ai = base[i2] + (fr[i2] >= cj ? 1 : 0);
            h ^= (uint32_t)(ai - prev) * PR[i2];
            prev = ai;
        }
        idx9[j] = h & (TBL - 1);
        w9[j]   = cj - prevc;
        prevc   = cj;
    }
}

// ---------------- encoding: level-major, asm-batched gathers ----------------
// 2048 blocks: block i -> level (i&7)+8*(i>>10); xcd = i%8 so each XCD's L2
// sees 2 of 16 level-tables. All 9 table loads forced in flight via inline asm.
__global__ __launch_bounds__(256) void k_encode(
    const float* __restrict__ x, const float* __restrict__ T,
    const float* __restrict__ Karr, unsigned short* __restrict__ h0T)
{
    int i = blockIdx.x;
    int l = (i & 7) + ((i >> 10) << 3);
    int b = ((i & 1023) >> 3) * 256 + threadIdx.x;

    const float4 x0 = *(const float4*)(x + (size_t)b * DD);
    const float4 x1 = *(const float4*)(x + (size_t)b * DD + 4);
    float xs[8] = {x0.x, x0.y, x0.z, x0.w, x1.x, x1.y, x1.z, x1.w};

    float Kl = Karr[l];
    const f32x2* Tl = (const f32x2*)(T + ((size_t)l * TBL) * 2);

    uint32_t idx9[9];
    float    w9[9];
    enc_idx(xs, Kl, idx9, w9);

    // force 9 independent gathers in flight, then one waitcnt
    f32x2 t0, t1, t2, t3, t4, t5, t6, t7, t8;
#define GL(n) asm volatile("global_load_dwordx2 %0, %1, off" \
                           : "=v"(t##n) : "v"(Tl + idx9[n]));
    GL(0) GL(1) GL(2) GL(3) GL(4) GL(5) GL(6) GL(7) GL(8)
#undef GL
    asm volatile("s_waitcnt vmcnt(0)"
        : "+v"(t0), "+v"(t1), "+v"(t2), "+v"(t3), "+v"(t4),
          "+v"(t5), "+v"(t6), "+v"(t7), "+v"(t8));
    __builtin_amdgcn_sched_barrier(0);

    float f0, f1;
    f0 = t0[0] * w9[0];  f1 = t0[1] * w9[0];
    f0 = fmaf(t1[0], w9[1], f0); f1 = fmaf(t1[1], w9[1], f1);
    f0 = fmaf(t2[0], w9[2], f0); f1 = fmaf(t2[1], w9[2], f1);
    f0 = fmaf(t3[0], w9[3], f0); f1 = fmaf(t3[1], w9[3], f1);
    f0 = fmaf(t4[0], w9[4], f0); f1 = fmaf(t4[1], w9[4], f1);
    f0 = fmaf(t5[0], w9[5], f0); f1 = fmaf(t5[1], w9[5], f1);
    f0 = fmaf(t6[0], w9[6], f0); f1 = fmaf(t6[1], w9[6], f1);
    f0 = fmaf(t7[0], w9[7], f0); f1 = fmaf(t7[1], w9[7], f1);
    f0 = fmaf(t8[0], w9[8], f0); f1 = fmaf(t8[1], w9[8], f1);
    f0 /= Kl;
    f1 /= Kl;

    h0T[(size_t)(l * 2 + 0) * BB + b] = f2bf(f0);
    h0T[(size_t)(l * 2 + 1) * BB + b] = f2bf(f1);
}

// ---------------- pack: planes + x -> row-major bf16 [B][64] (zero-padded K) ----
__global__ __launch_bounds__(256) void k_pack(
    const unsigned short* __restrict__ h0T, const float* __restrict__ x,
    unsigned short* __restrict__ h0b)
{
    int b = blockIdx.x * 256 + threadIdx.x;
    unsigned short row[64];
    const float4 x0 = *(const float4*)(x + (size_t)b * 8);
    const float4 x1 = *(const float4*)(x + (size_t)b * 8 + 4);
    row[0] = f2bf(x0.x); row[1] = f2bf(x0.y); row[2] = f2bf(x0.z); row[3] = f2bf(x0.w);
    row[4] = f2bf(x1.x); row[5] = f2bf(x1.y); row[6] = f2bf(x1.z); row[7] = f2bf(x1.w);
#pragma unroll
    for (int p = 0; p < 32; p++) row[8 + p] = h0T[(size_t)p * BB + b];
#pragma unroll
    for (int c = 40; c < 64; c++) row[c] = 0;
#pragma unroll
    for (int i = 0; i < 8; i++)
        *(u16x8*)(h0b + (size_t)b * 64 + i * 8) = *(u16x8*)(row + i * 8);
}

// ---------------- weight converts ----------------
__global__ __launch_bounds__(256) void k_cvt(
    const float* __restrict__ w, unsigned short* __restrict__ o)
{
    int i = blockIdx.x * 256 + threadIdx.x;     // each converts 4
    float4 v = *(const float4*)(w + (size_t)i * 4);
    ushort4 r;
    r.x = f2bf(v.x); r.y = f2bf(v.y); r.z = f2bf(v.z); r.w = f2bf(v.w);
    *(ushort4*)(o + (size_t)i * 4) = r;
}

__global__ __launch_bounds__(256) void k_cvt1(
    const float* __restrict__ w, unsigned short* __restrict__ o)  // [512][40] -> [512][64] pad
{
    int i = blockIdx.x * 256 + threadIdx.x;     // 8192 threads
    int row = i >> 4, c4 = (i & 15) * 4;
    ushort4 r = make_ushort4(0, 0, 0, 0);
    if (c4 < 40) {
        float4 v = *(const float4*)(w + (size_t)row * 40 + c4);
        r.x = f2bf(v.x); r.y = f2bf(v.y); r.z = f2bf(v.z); r.w = f2bf(v.w);
    }
    *(ushort4*)(o + (size_t)row * 64 + c4) = r;
}

// ------- unified bf16 MFMA GEMM: Out[M][512] = relu(A[M][K] @ Bw[512][K]^T + bias) -------
template<int KK>
__global__ __launch_bounds__(256) void k_mgemm(
    const unsigned short* __restrict__ A, const unsigned short* __restrict__ Bw,
    const float* __restrict__ bias, unsigned short* __restrict__ Out)
{
    __shared__ unsigned short As[128 * 64];   // physical (swizzled) layout
    __shared__ unsigned short Bs[128 * 64];

    const int tid  = threadIdx.x;
    const int wid  = tid >> 6;
    const int lane = tid & 63;
    const int wm = wid >> 1, wn = wid & 1;
    const int lr = lane & 15;
    const int kg = lane >> 4;

    const int b0 = blockIdx.x * 128;
    const int o0 = blockIdx.y * 128;

    f32x4 acc[4][4] = {};

    for (int k0 = 0; k0 < KK; k0 += 64) {
        // stage A,B tiles: inverse-swizzled global source, linear LDS dest
#pragma unroll
        for (int it = 0; it < 4; ++it) {
            int offb  = (it * 256 + tid) << 4;
            int loffb = offb ^ (((offb >> 7) & 7) << 4);
            int row = loffb >> 7;            // 0..127
            int kel = (loffb & 127) >> 1;    // 0..63, multiple of 8
            int ldsbyte = ((it * 256) + (wid * 64)) << 4;  // wave-uniform base
            gload_lds16(A  + (size_t)(b0 + row) * KK + k0 + kel, (char*)As + ldsbyte);
            gload_lds16(Bw + (size_t)(o0 + row) * KK + k0 + kel, (char*)Bs + ldsbyte);
        }
        __syncthreads();

#pragma unroll
        for (int ks = 0; ks < 2; ++ks) {
            short8 af[4], bfr[4];
            int kbyte = ks * 64 + kg * 16;
#pragma unroll
            for (int m = 0; m < 4; ++m) {
                int row = wm * 64 + m * 16 + lr;
                int a = ((row << 7) + kbyte) ^ ((row & 7) << 4);
                af[m] = *(const short8*)((const char*)As + a);
            }
#pragma unroll
            for (int n = 0; n < 4; ++n) {
                int col = wn * 64 + n * 16 + lr;
                int a = ((col << 7) + kbyte) ^ ((col & 7) << 4);
                bfr[n] = *(const short8*)((const char*)Bs + a);
            }
#pragma unroll
            for (int m = 0; m < 4; ++m)
#pragma unroll
                for (int n = 0; n < 4; ++n)
                    acc[m][n] = __builtin_amdgcn_mfma_f32_16x16x32_bf16(
                        af[m], bfr[n], acc[m][n], 0, 0, 0);
        }
        __syncthreads();
    }

    // epilogue: bias + relu, bf16 store. C/D layout: col=lane&15, row=(lane>>4)*4+r
#pragma unroll
    for (int n = 0; n < 4; ++n) {
        int col = o0 + wn * 64 + n * 16 + lr;
        float bv = bias[col];
#pragma unroll
        for (int m = 0; m < 4; ++m) {
            int rbase = b0 + wm * 64 + m * 16 + (lane >> 4) * 4;
#pragma unroll
            for (int r = 0; r < 4; ++r) {
                float v = fmaxf(acc[m][n][r] + bv, 0.f);
                Out[(size_t)(rbase + r) * HID + col] = f2bf(v);
            }
        }
    }
}

// ---------------- heads: action/value from bf16 h2, one wave per sample ----------------
__global__ __launch_bounds__(256) void k_heads(
    const unsigned short* __restrict__ h2, const float* __restrict__ aw,
    const float* __restrict__ ab, const float* __restrict__ vw,
    const float* __restrict__ vb, float* __restrict__ out)
{
    int wave = threadIdx.x >> 6;
    int lane = threadIdx.x & 63;
    int s = blockIdx.x * 4 + wave;

    const unsigned short* hr = h2 + (size_t)s * HID + lane * 8;
    u16x8 hu = *(const u16x8*)hr;
    float hv[8];
#pragma unroll
    for (int j = 0; j < 8; j++) hv[j] = bf2f(hu[j]);

    float part[5];
#pragma unroll
    for (int m = 0; m < 5; m++) {
        const float* wrow = ((m < 4) ? (aw + (size_t)m * HID) : vw) + lane * 8;
        float4 wa = *(const float4*)wrow;
        float4 wb = *(const float4*)(wrow + 4);
        float p = hv[0] * wa.x;
        p = fmaf(hv[1], wa.y, p);
        p = fmaf(hv[2], wa.z, p);
        p = fmaf(hv[3], wa.w, p);
        p = fmaf(hv[4], wb.x, p);
        p = fmaf(hv[5], wb.y, p);
        p = fmaf(hv[6], wb.z, p);
        p = fmaf(hv[7], wb.w, p);
        part[m] = p;
    }
#pragma unroll
    for (int m = 0; m < 5; m++) {
        float v = part[m];
#pragma unroll
        for (int off = 32; off > 0; off >>= 1) v += __shfl_xor(v, off);
        if (lane == 0) {
            if (m < 4) out[(size_t)s * 4 + m] = v + ab[m];
            else       out[(size_t)BB * 4 + s] = v + vb[0];
        }
    }
}

extern "C" void kernel_launch(void* const* d_in, const int* in_sizes, int n_in,
                              void* d_out, int out_size, void* d_ws, size_t ws_size,
                              hipStream_t stream)
{
    const float* x    = (const float*)d_in[0];
    const float* T    = (const float*)d_in[1];
    const float* K    = (const float*)d_in[2];
    const float* l1w  = (const float*)d_in[3];
    const float* l1b  = (const float*)d_in[4];
    const float* l2w  = (const float*)d_in[5];
    const float* l2b  = (const float*)d_in[6];
    const float* actw = (const float*)d_in[7];
    const float* actb = (const float*)d_in[8];
    const float* valw = (const float*)d_in[9];
    const float* valb = (const float*)d_in[10];
    float* out = (float*)d_out;

    char* ws = (char*)d_ws;
    unsigned short* h0b = (unsigned short*)ws;                    // B*64 bf16  = 4,194,304 B
    unsigned short* h1  = (unsigned short*)(ws + 4194304);        // B*512 bf16 = 33,554,432 B
    unsigned short* h2  = (unsigned short*)(ws + 37748736);       // B*512 bf16 = 33,554,432 B
    unsigned short* w2b = (unsigned short*)(ws + 71303168);       // 512*512 bf16 = 524,288 B
    unsigned short* w1b = (unsigned short*)(ws + 71827456);       // 512*64 bf16  = 65,536 B
    // h0T planes alias the h2 region: consumed by k_pack before k_mgemm<512> writes h2
    unsigned short* h0T = h2;                                     // 32*B bf16 = 2,097,152 B

    k_encode    <<<2048, 256, 0, stream>>>(x, T, K, h0T);
    k_cvt       <<<HID * HID / 4 / 256, 256, 0, stream>>>(l2w, w2b);
    k_cvt1      <<<32, 256, 0, stream>>>(l1w, w1b);
    k_pack      <<<BB / 256, 256, 0, stream>>>(h0T, x, h0b);
    k_mgemm<64> <<<dim3(BB / 128, 4), 256, 0, stream>>>(h0b, w1b, l1b, h1);
    k_mgemm<512><<<dim3(BB / 128, 4), 256, 0, stream>>>(h1, w2b, l2b, h2);
    k_heads     <<<BB / 4, 256, 0, stream>>>(h2, actw, actb, valw, valb, out);
}

// Round 7
// 86.347 us; speedup vs baseline: 4.1241x; 1.0629x over previous
//
#include <hip/hip_runtime.h>
#include <cstdint>
#include <cstddef>

#define BB   32768
#define DD   8
#define LLV  16
#define TBL  524288
#define HID  512

typedef __attribute__((ext_vector_type(8))) short short8;
typedef __attribute__((ext_vector_type(8))) unsigned short u16x8;
typedef __attribute__((ext_vector_type(4))) float f32x4;
typedef __attribute__((ext_vector_type(2))) float f32x2;

// primes mod 2^32
__device__ __constant__ uint32_t PR[8] = {
    2654436881u, 1620619981u, 1500450271u, 3267000013u,
    1459886047u, 4093082899u,  986956175u, 3628273133u
};

__device__ __forceinline__ unsigned short f2bf(float f) {
    uint32_t u = __float_as_uint(f);
    uint32_t r = (u + 0x7fffu + ((u >> 16) & 1u)) >> 16;   // RNE
    return (unsigned short)r;
}
__device__ __forceinline__ float bf2f(unsigned short u) {
    return __uint_as_float(((uint32_t)u) << 16);
}

__device__ __forceinline__ void gload_lds16(const void* gsrc, void* ldst) {
    __builtin_amdgcn_global_load_lds(
        (const __attribute__((address_space(1))) unsigned int*)gsrc,
        (__attribute__((address_space(3))) unsigned int*)ldst,
        16, 0, 0);
}

// per-sample: cumsum -> sort -> 9 vertex hashes + weights
__device__ __forceinline__ void enc_idx(const float xs[8], float Kl,
                                        uint32_t idx9[9], float w9[9])
{
    float fr[8];
    int   base[8];
    float cs = 0.f;
#pragma unroll
    for (int i2 = 0; i2 < 8; i2++) {
        cs += xs[i2];                 // sequential fp32 cumsum (matches np)
        float p = cs * Kl;
        fr[i2]   = p - truncf(p);
        base[i2] = (int)floorf(p);
    }

    float c[8];
#pragma unroll
    for (int i2 = 0; i2 < 8; i2++) c[i2] = fr[i2];
#define CE(a_, b_) { float lo_ = fminf(c[a_], c[b_]); float hi_ = fmaxf(c[a_], c[b_]); c[a_] = lo_; c[b_] = hi_; }
    CE(0,1) CE(2,3) CE(4,5) CE(6,7)
    CE(0,2) CE(1,3) CE(4,6) CE(5,7)
    CE(1,2) CE(5,6) CE(0,4) CE(3,7)
    CE(1,5) CE(2,6)
    CE(1,4) CE(3,6)
    CE(2,4) CE(3,5)
    CE(3,4)
#undef CE

    float prevc = 0.f;
#pragma unroll
    for (int j = 0; j < 9; j++) {
        float cj = (j < 8) ? c[j] : 1.0f;
        uint32_t h = 0;
        int prev = 0;
#pragma unroll
        for (int i2 = 0; i2 < 8; i2++) {
            int ai = base[i2] + (fr[i2] >= cj ? 1 : 0);
            h ^= (uint32_t)(ai - prev) * PR[i2];
            prev = ai;
        }
        idx9[j] = h & (TBL - 1);
        w9[j]   = cj - prevc;
        prevc   = cj;
    }
}

// ---------------- encoding: level-major, asm-batched gathers ----------------
__global__ __launch_bounds__(256) void k_encode(
    const float* __restrict__ x, const float* __restrict__ T,
    const float* __restrict__ Karr, unsigned short* __restrict__ h0T)
{
    int i = blockIdx.x;
    int l = (i & 7) + ((i >> 10) << 3);
    int b = ((i & 1023) >> 3) * 256 + threadIdx.x;

    const float4 x0 = *(const float4*)(x + (size_t)b * DD);
    const float4 x1 = *(const float4*)(x + (size_t)b * DD + 4);
    float xs[8] = {x0.x, x0.y, x0.z, x0.w, x1.x, x1.y, x1.z, x1.w};

    float Kl = Karr[l];
    const f32x2* Tl = (const f32x2*)(T + ((size_t)l * TBL) * 2);

    uint32_t idx9[9];
    float    w9[9];
    enc_idx(xs, Kl, idx9, w9);

    f32x2 t0, t1, t2, t3, t4, t5, t6, t7, t8;
#define GL(n) asm volatile("global_load_dwordx2 %0, %1, off" \
                           : "=v"(t##n) : "v"(Tl + idx9[n]));
    GL(0) GL(1) GL(2) GL(3) GL(4) GL(5) GL(6) GL(7) GL(8)
#undef GL
    asm volatile("s_waitcnt vmcnt(0)"
        : "+v"(t0), "+v"(t1), "+v"(t2), "+v"(t3), "+v"(t4),
          "+v"(t5), "+v"(t6), "+v"(t7), "+v"(t8));
    __builtin_amdgcn_sched_barrier(0);

    float f0, f1;
    f0 = t0[0] * w9[0];  f1 = t0[1] * w9[0];
    f0 = fmaf(t1[0], w9[1], f0); f1 = fmaf(t1[1], w9[1], f1);
    f0 = fmaf(t2[0], w9[2], f0); f1 = fmaf(t2[1], w9[2], f1);
    f0 = fmaf(t3[0], w9[3], f0); f1 = fmaf(t3[1], w9[3], f1);
    f0 = fmaf(t4[0], w9[4], f0); f1 = fmaf(t4[1], w9[4], f1);
    f0 = fmaf(t5[0], w9[5], f0); f1 = fmaf(t5[1], w9[5], f1);
    f0 = fmaf(t6[0], w9[6], f0); f1 = fmaf(t6[1], w9[6], f1);
    f0 = fmaf(t7[0], w9[7], f0); f1 = fmaf(t7[1], w9[7], f1);
    f0 = fmaf(t8[0], w9[8], f0); f1 = fmaf(t8[1], w9[8], f1);
    f0 /= Kl;
    f1 /= Kl;

    h0T[(size_t)(l * 2 + 0) * BB + b] = f2bf(f0);
    h0T[(size_t)(l * 2 + 1) * BB + b] = f2bf(f1);
}

// ---------------- pack: planes + x -> row-major bf16 [B][64] (zero-padded K) ----
__global__ __launch_bounds__(256) void k_pack(
    const unsigned short* __restrict__ h0T, const float* __restrict__ x,
    unsigned short* __restrict__ h0b)
{
    int b = blockIdx.x * 256 + threadIdx.x;
    unsigned short row[64];
    const float4 x0 = *(const float4*)(x + (size_t)b * 8);
    const float4 x1 = *(const float4*)(x + (size_t)b * 8 + 4);
    row[0] = f2bf(x0.x); row[1] = f2bf(x0.y); row[2] = f2bf(x0.z); row[3] = f2bf(x0.w);
    row[4] = f2bf(x1.x); row[5] = f2bf(x1.y); row[6] = f2bf(x1.z); row[7] = f2bf(x1.w);
#pragma unroll
    for (int p = 0; p < 32; p++) row[8 + p] = h0T[(size_t)p * BB + b];
#pragma unroll
    for (int c = 40; c < 64; c++) row[c] = 0;
#pragma unroll
    for (int i = 0; i < 8; i++)
        *(u16x8*)(h0b + (size_t)b * 64 + i * 8) = *(u16x8*)(row + i * 8);
}

// ---------------- weight converts ----------------
__global__ __launch_bounds__(256) void k_cvt(
    const float* __restrict__ w, unsigned short* __restrict__ o)
{
    int i = blockIdx.x * 256 + threadIdx.x;
    float4 v = *(const float4*)(w + (size_t)i * 4);
    ushort4 r;
    r.x = f2bf(v.x); r.y = f2bf(v.y); r.z = f2bf(v.z); r.w = f2bf(v.w);
    *(ushort4*)(o + (size_t)i * 4) = r;
}

__global__ __launch_bounds__(256) void k_cvt1(
    const float* __restrict__ w, unsigned short* __restrict__ o)  // [512][40] -> [512][64]
{
    int i = blockIdx.x * 256 + threadIdx.x;
    int row = i >> 4, c4 = (i & 15) * 4;
    ushort4 r = make_ushort4(0, 0, 0, 0);
    if (c4 < 40) {
        float4 v = *(const float4*)(w + (size_t)row * 40 + c4);
        r.x = f2bf(v.x); r.y = f2bf(v.y); r.z = f2bf(v.z); r.w = f2bf(v.w);
    }
    *(ushort4*)(o + (size_t)row * 64 + c4) = r;
}

// ------- unified bf16 MFMA GEMM, 2-phase dbuf; FUSE=1 adds head-partial epilogue -------
template<int KK, int FUSE>
__global__ __launch_bounds__(256) void k_mgemm(
    const unsigned short* __restrict__ A, const unsigned short* __restrict__ Bw,
    const float* __restrict__ bias, unsigned short* __restrict__ Out,
    const float* __restrict__ aw, const float* __restrict__ vw,
    float* __restrict__ hpart)
{
    __shared__ unsigned short As[2][128 * 64];   // swizzled physical layout
    __shared__ unsigned short Bs[2][128 * 64];

    const int tid  = threadIdx.x;
    const int wid  = tid >> 6;
    const int lane = tid & 63;
    const int wm = wid >> 1, wn = wid & 1;
    const int lr = lane & 15;
    const int kg = lane >> 4;

    const int b0 = blockIdx.x * 128;
    const int o0 = blockIdx.y * 128;

    f32x4 acc[4][4] = {};

    constexpr int NT = KK / 64;

#define STAGE(buf, k0)                                                          \
    {                                                                           \
        _Pragma("unroll")                                                       \
        for (int it = 0; it < 4; ++it) {                                        \
            int offb  = (it * 256 + tid) << 4;                                  \
            int loffb = offb ^ (((offb >> 7) & 7) << 4);                        \
            int row = loffb >> 7;                                               \
            int kel = (loffb & 127) >> 1;                                       \
            int ldsbyte = (buf) * 16384 + (((it * 256) + (wid * 64)) << 4);     \
            gload_lds16(A  + (size_t)(b0 + row) * KK + (k0) + kel,              \
                        (char*)As + ldsbyte);                                   \
            gload_lds16(Bw + (size_t)(o0 + row) * KK + (k0) + kel,              \
                        (char*)Bs + ldsbyte);                                   \
        }                                                                       \
    }

#define COMPUTE(buf)                                                            \
    {                                                                           \
        _Pragma("unroll")                                                       \
        for (int ks = 0; ks < 2; ++ks) {                                        \
            short8 af[4], bfr[4];                                               \
            int kbyte = ks * 64 + kg * 16;                                      \
            _Pragma("unroll")                                                   \
            for (int m = 0; m < 4; ++m) {                                       \
                int row = wm * 64 + m * 16 + lr;                                \
                int a = (buf) * 16384 + ((((row << 7) + kbyte)) ^ ((row & 7) << 4)); \
                af[m] = *(const short8*)((const char*)As + a);                  \
            }                                                                   \
            _Pragma("unroll")                                                   \
            for (int n = 0; n < 4; ++n) {                                       \
                int col = wn * 64 + n * 16 + lr;                                \
                int a = (buf) * 16384 + ((((col << 7) + kbyte)) ^ ((col & 7) << 4)); \
                bfr[n] = *(const short8*)((const char*)Bs + a);                 \
            }                                                                   \
            _Pragma("unroll")                                                   \
            for (int m = 0; m < 4; ++m)                                         \
                _Pragma("unroll")                                               \
                for (int n = 0; n < 4; ++n)                                     \
                    acc[m][n] = __builtin_amdgcn_mfma_f32_16x16x32_bf16(        \
                        af[m], bfr[n], acc[m][n], 0, 0, 0);                     \
        }                                                                       \
    }

    STAGE(0, 0)
    __syncthreads();                 // implicit vmcnt(0) drain before barrier
    int cur = 0;
#pragma unroll
    for (int t = 0; t < NT - 1; ++t) {
        STAGE(cur ^ 1, (t + 1) * 64)     // issue next tile's loads first
        COMPUTE(cur)                     // MFMA on current while loads fly
        __syncthreads();                 // drain + all waves done reading cur
        cur ^= 1;
    }
    COMPUTE(cur)
#undef STAGE
#undef COMPUTE

    float bo[4];
#pragma unroll
    for (int n = 0; n < 4; ++n) bo[n] = bias[o0 + wn * 64 + n * 16 + lr];

    if constexpr (FUSE) {
        // relu+bias in place (fp32)
#pragma unroll
        for (int m = 0; m < 4; ++m)
#pragma unroll
            for (int n = 0; n < 4; ++n)
#pragma unroll
                for (int r = 0; r < 4; ++r)
                    acc[m][n][r] = fmaxf(acc[m][n][r] + bo[n], 0.f);

        // head weights for this thread's 4 columns
        float hwv[5][4];
#pragma unroll
        for (int n = 0; n < 4; ++n) {
            int cg = o0 + wn * 64 + n * 16 + lr;
            hwv[0][n] = aw[cg];
            hwv[1][n] = aw[512 + cg];
            hwv[2][n] = aw[1024 + cg];
            hwv[3][n] = aw[1536 + cg];
            hwv[4][n] = vw[cg];
        }
        float* hp = hpart + (size_t)(blockIdx.y * 2 + wn) * (BB * 5);
#pragma unroll
        for (int hm = 0; hm < 5; ++hm) {
            f32x4 p[4];
#pragma unroll
            for (int m = 0; m < 4; ++m) {
                p[m] = acc[m][0] * hwv[hm][0];
                p[m] += acc[m][1] * hwv[hm][1];
                p[m] += acc[m][2] * hwv[hm][2];
                p[m] += acc[m][3] * hwv[hm][3];
            }
            // reduce over the 16 lr-lanes (kg preserved)
#pragma unroll
            for (int d = 1; d < 16; d <<= 1)
#pragma unroll
                for (int m = 0; m < 4; ++m)
#pragma unroll
                    for (int r = 0; r < 4; ++r)
                        p[m][r] += __shfl_xor(p[m][r], d);
            if (lr == 0) {
#pragma unroll
                for (int m = 0; m < 4; ++m)
#pragma unroll
                    for (int r = 0; r < 4; ++r)
                        hp[(size_t)(b0 + wm * 64 + m * 16 + kg * 4 + r) * 5 + hm] = p[m][r];
            }
        }
    } else {
        // bf16 store. C/D layout: col=lane&15, row=(lane>>4)*4+r
#pragma unroll
        for (int n = 0; n < 4; ++n) {
            int col = o0 + wn * 64 + n * 16 + lr;
#pragma unroll
            for (int m = 0; m < 4; ++m) {
                int rbase = b0 + wm * 64 + m * 16 + kg * 4;
#pragma unroll
                for (int r = 0; r < 4; ++r) {
                    float v = fmaxf(acc[m][n][r] + bo[n], 0.f);
                    Out[(size_t)(rbase + r) * HID + col] = f2bf(v);
                }
            }
        }
    }
}

// ---------------- reduce 8 head-partial slots + bias -> out ----------------
__global__ __launch_bounds__(256) void k_hreduce(
    const float* __restrict__ hpart, const float* __restrict__ ab,
    const float* __restrict__ vb, float* __restrict__ out)
{
    int i = blockIdx.x * 256 + threadIdx.x;    // 0 .. BB*5-1, = b*5+hm
    int b = i / 5;
    int hm = i - b * 5;
    float s = 0.f;
#pragma unroll
    for (int g = 0; g < 8; ++g) s += hpart[(size_t)g * (BB * 5) + i];
    s += (hm < 4) ? ab[hm] : vb[0];
    if (hm < 4) out[(size_t)b * 4 + hm] = s;
    else        out[(size_t)BB * 4 + b] = s;
}

extern "C" void kernel_launch(void* const* d_in, const int* in_sizes, int n_in,
                              void* d_out, int out_size, void* d_ws, size_t ws_size,
                              hipStream_t stream)
{
    const float* x    = (const float*)d_in[0];
    const float* T    = (const float*)d_in[1];
    const float* K    = (const float*)d_in[2];
    const float* l1w  = (const float*)d_in[3];
    const float* l1b  = (const float*)d_in[4];
    const float* l2w  = (const float*)d_in[5];
    const float* l2b  = (const float*)d_in[6];
    const float* actw = (const float*)d_in[7];
    const float* actb = (const float*)d_in[8];
    const float* valw = (const float*)d_in[9];
    const float* valb = (const float*)d_in[10];
    float* out = (float*)d_out;

    char* ws = (char*)d_ws;
    unsigned short* h0b   = (unsigned short*)ws;                   // B*64 bf16   = 4,194,304 B
    unsigned short* h1    = (unsigned short*)(ws + 4194304);       // B*512 bf16  = 33,554,432 B
    unsigned short* h0T   = (unsigned short*)(ws + 37748736);      // 32*B bf16   = 2,097,152 B
    unsigned short* w2b   = (unsigned short*)(ws + 39845888);      // 512*512 bf16= 524,288 B
    unsigned short* w1b   = (unsigned short*)(ws + 40370176);      // 512*64 bf16 = 65,536 B
    float*          hpart = (float*)(ws + 40435712);               // 8*B*5 f32   = 5,242,880 B

    k_encode        <<<2048, 256, 0, stream>>>(x, T, K, h0T);
    k_cvt           <<<HID * HID / 4 / 256, 256, 0, stream>>>(l2w, w2b);
    k_cvt1          <<<32, 256, 0, stream>>>(l1w, w1b);
    k_pack          <<<BB / 256, 256, 0, stream>>>(h0T, x, h0b);
    k_mgemm<64, 0>  <<<dim3(BB / 128, 4), 256, 0, stream>>>(h0b, w1b, l1b, h1,
                                                            nullptr, nullptr, nullptr);
    k_mgemm<512, 1> <<<dim3(BB / 128, 4), 256, 0, stream>>>(h1, w2b, l2b, nullptr,
                                                            actw, valw, hpart);
    k_hreduce       <<<BB * 5 / 256, 256, 0, stream>>>(hpart, actb, valb, out);
}